// Round 7
// baseline (242.260 us; speedup 1.0000x reference)
//
#include <hip/hip_runtime.h>

#define S_LEN 2048
#define BATCH 2
#define DM    1024
#define NH    16
#define NKV   4
#define HD    64
#define MROWS (BATCH * S_LEN)   // 4096
#define NQKV  1536              // 1024 q + 512 kv

typedef __attribute__((ext_vector_type(8))) short bf16x8;
typedef __attribute__((ext_vector_type(4))) short s16x4;
typedef __attribute__((ext_vector_type(4))) float f32x4;

__device__ __forceinline__ unsigned short f2bf(float f) {
  unsigned int u = __float_as_uint(f);
  u += 0x7FFF + ((u >> 16) & 1);   // RNE
  return (unsigned short)(u >> 16);
}

__device__ __forceinline__ void gload_lds16(const unsigned short* g, unsigned short* l) {
  __builtin_amdgcn_global_load_lds((const __attribute__((address_space(1))) void*)g,
                                   (__attribute__((address_space(3))) void*)l, 16, 0, 0);
}

// ---------------- x -> bf16 ----------------
__global__ __launch_bounds__(256) void cvt_x_kernel(const float* __restrict__ x,
                                                    unsigned short* __restrict__ xb, int n) {
  int i = (blockIdx.x * 256 + threadIdx.x) * 4;
  if (i < n) {
    float4 v = *reinterpret_cast<const float4*>(x + i);
    xb[i + 0] = f2bf(v.x);
    xb[i + 1] = f2bf(v.y);
    xb[i + 2] = f2bf(v.z);
    xb[i + 3] = f2bf(v.w);
  }
}

// ---------------- W (RxC fp32) -> W^T (CxR bf16) ----------------
__global__ __launch_bounds__(256) void transpose_cvt_kernel(const float* __restrict__ in,
                                                            unsigned short* __restrict__ out,
                                                            int R, int C) {
  __shared__ float tile[64][65];
  int r0 = blockIdx.y * 64, c0 = blockIdx.x * 64;
  int t = threadIdx.x;
  int rl = t >> 2, cs = (t & 3) * 16;
#pragma unroll
  for (int k = 0; k < 4; ++k) {
    float4 v = *reinterpret_cast<const float4*>(in + (size_t)(r0 + rl) * C + c0 + cs + 4 * k);
    tile[rl][cs + 4 * k + 0] = v.x;
    tile[rl][cs + 4 * k + 1] = v.y;
    tile[rl][cs + 4 * k + 2] = v.z;
    tile[rl][cs + 4 * k + 3] = v.w;
  }
  __syncthreads();
  int cl = t >> 2, rs = (t & 3) * 16;
  bf16x8 v0, v1;
#pragma unroll
  for (int i = 0; i < 8; ++i) v0[i] = (short)f2bf(tile[rs + i][cl]);
#pragma unroll
  for (int i = 0; i < 8; ++i) v1[i] = (short)f2bf(tile[rs + 8 + i][cl]);
  unsigned short* dst = out + (size_t)(c0 + cl) * R + r0 + rs;
  *reinterpret_cast<bf16x8*>(dst) = v0;
  *reinterpret_cast<bf16x8*>(dst + 8) = v1;
}

// ------- bf16 GEMM, split-K(2), m97 structure: global_load_lds staging -------
__global__ __launch_bounds__(256) void gemm_bt_splitk(const unsigned short* __restrict__ A,
                                                      const unsigned short* __restrict__ BT,
                                                      float* __restrict__ Cp,
                                                      int M, int N, int Kpart, int Ktot) {
  __shared__ __align__(16) unsigned short As[128 * 64];
  __shared__ __align__(16) unsigned short Bs[128 * 64];
  int z = blockIdx.z;
  float* C = Cp + (size_t)z * M * N;
  int kbeg = z * Kpart;
  int row0 = blockIdx.y * 128, col0 = blockIdx.x * 128;
  int t = threadIdx.x;
  int w = t >> 6, lane = t & 63, quad = lane >> 4, l16 = lane & 15;
  int wm = w & 1, wn = w >> 1;
  int srow = lane >> 3;
  int scol = (lane & 7) * 8;

  f32x4 acc[4][4];
#pragma unroll
  for (int i = 0; i < 4; ++i)
#pragma unroll
    for (int j = 0; j < 4; ++j) acc[i][j] = (f32x4){0.f, 0.f, 0.f, 0.f};

  for (int k0 = kbeg; k0 < kbeg + Kpart; k0 += 64) {
#pragma unroll
    for (int j = 0; j < 4; ++j) {
      int r = w * 32 + j * 8 + srow;
      gload_lds16(A + (size_t)(row0 + r) * Ktot + k0 + scol, &As[(w * 32 + j * 8) * 64]);
      gload_lds16(BT + (size_t)(col0 + r) * Ktot + k0 + scol, &Bs[(w * 32 + j * 8) * 64]);
    }
    __syncthreads();
#pragma unroll
    for (int ks = 0; ks < 2; ++ks) {
      bf16x8 af[4], bfr[4];
#pragma unroll
      for (int i = 0; i < 4; ++i)
        af[i] = *reinterpret_cast<const bf16x8*>(&As[(wm * 64 + i * 16 + l16) * 64 + ks * 32 + quad * 8]);
#pragma unroll
      for (int i = 0; i < 4; ++i)
        bfr[i] = *reinterpret_cast<const bf16x8*>(&Bs[(wn * 64 + i * 16 + l16) * 64 + ks * 32 + quad * 8]);
#pragma unroll
      for (int am = 0; am < 4; ++am)
#pragma unroll
        for (int bn = 0; bn < 4; ++bn)
          acc[am][bn] = __builtin_amdgcn_mfma_f32_16x16x32_bf16(af[am], bfr[bn], acc[am][bn], 0, 0, 0);
    }
    __syncthreads();
  }
#pragma unroll
  for (int am = 0; am < 4; ++am)
#pragma unroll
    for (int bn = 0; bn < 4; ++bn) {
      int row = row0 + wm * 64 + am * 16 + quad * 4;
      float* Cptr = C + (size_t)row * N + col0 + wn * 64 + bn * 16 + l16;
#pragma unroll
      for (int rg = 0; rg < 4; ++rg) Cptr[(size_t)rg * N] = acc[am][bn][rg];
    }
}

// ------- bf16 GEMM, 128x64 tile, no split-K, direct fp32 C -------
__global__ __launch_bounds__(256) void gemm_bt_n64(const unsigned short* __restrict__ A,
                                                   const unsigned short* __restrict__ BT,
                                                   float* __restrict__ C,
                                                   int M, int N, int K) {
  __shared__ __align__(16) unsigned short As[128 * 64];
  __shared__ __align__(16) unsigned short Bs[64 * 64];
  int row0 = blockIdx.y * 128, col0 = blockIdx.x * 64;
  int t = threadIdx.x;
  int w = t >> 6, lane = t & 63, quad = lane >> 4, l16 = lane & 15;
  int srow = lane >> 3;
  int scol = (lane & 7) * 8;

  f32x4 acc[2][4];
#pragma unroll
  for (int i = 0; i < 2; ++i)
#pragma unroll
    for (int j = 0; j < 4; ++j) acc[i][j] = (f32x4){0.f, 0.f, 0.f, 0.f};

  for (int k0 = 0; k0 < K; k0 += 64) {
#pragma unroll
    for (int j = 0; j < 4; ++j)
      gload_lds16(A + (size_t)(row0 + w * 32 + j * 8 + srow) * K + k0 + scol,
                  &As[(w * 32 + j * 8) * 64]);
#pragma unroll
    for (int j = 0; j < 2; ++j)
      gload_lds16(BT + (size_t)(col0 + w * 16 + j * 8 + srow) * K + k0 + scol,
                  &Bs[(w * 16 + j * 8) * 64]);
    __syncthreads();
#pragma unroll
    for (int ks = 0; ks < 2; ++ks) {
      bf16x8 af[2], bfr[4];
#pragma unroll
      for (int i = 0; i < 2; ++i)
        af[i] = *reinterpret_cast<const bf16x8*>(&As[(w * 32 + i * 16 + l16) * 64 + ks * 32 + quad * 8]);
#pragma unroll
      for (int j = 0; j < 4; ++j)
        bfr[j] = *reinterpret_cast<const bf16x8*>(&Bs[(j * 16 + l16) * 64 + ks * 32 + quad * 8]);
#pragma unroll
      for (int i = 0; i < 2; ++i)
#pragma unroll
        for (int j = 0; j < 4; ++j)
          acc[i][j] = __builtin_amdgcn_mfma_f32_16x16x32_bf16(af[i], bfr[j], acc[i][j], 0, 0, 0);
    }
    __syncthreads();
  }
#pragma unroll
  for (int i = 0; i < 2; ++i)
#pragma unroll
    for (int j = 0; j < 4; ++j) {
      int row = row0 + w * 32 + i * 16 + quad * 4;
      float* Cptr = C + (size_t)row * N + col0 + j * 16 + l16;
#pragma unroll
      for (int rg = 0; rg < 4; ++rg) Cptr[(size_t)rg * N] = acc[i][j][rg];
    }
}

// ---------------- RMSNorm + RoPE (reads the two split-K partials) ----------------
__global__ __launch_bounds__(256) void norm_rope_kernel(const float* __restrict__ qkv,
                                                        const float* __restrict__ q_scale,
                                                        const float* __restrict__ k_scale,
                                                        unsigned short* __restrict__ qb,
                                                        unsigned short* __restrict__ kbuf) {
  const size_t HALFQ = (size_t)MROWS * NQKV;
  int wid = (blockIdx.x * 256 + threadIdx.x) >> 6;
  int lane = threadIdx.x & 63;
  int r = wid / 20, hh = wid % 20;         // r = b*S + s
  int b = r >> 11, s = r & 2047;
  size_t sidx;
  const float* scale;
  unsigned short* dst;
  float post;
  if (hh < 16) {
    sidx = (size_t)r * NQKV + hh * 64;
    scale = q_scale;
    dst = qb + ((size_t)(b * NH + hh) * S_LEN + s) * HD;
    post = 1.0f;
  } else {
    int kvh = hh - 16;
    sidx = (size_t)r * NQKV + 1024 + kvh * 64;
    scale = k_scale;
    dst = kbuf + ((size_t)(b * NKV + kvh) * S_LEN + s) * HD;
    post = 0.125f * 1.44269504088896f;   // fold score scale + log2(e) into k
  }
  float v = qkv[sidx + lane] + qkv[sidx + HALFQ + lane];
  float ss = v * v;
#pragma unroll
  for (int m = 1; m < 64; m <<= 1) ss += __shfl_xor(ss, m, 64);
  float rms = sqrtf(ss * (1.0f / 64.0f) + 1e-5f);
  float nv = v / rms * scale[lane];
  int dh = lane & 31;
  float inv = exp2f((float)dh * (-13.2877123795495f / 32.0f));  // 10000^(-dh/32)
  float f = (float)s * inv;
  float c = cosf(f), sn = sinf(f);
  float partner = __shfl_xor(nv, 32, 64);
  float outv = (lane < 32) ? (nv * c - partner * sn) : (partner * sn + nv * c);
  dst[lane] = f2bf(outv * post);
}

// ------- V: (s,d) fp32 slice of qkv partials -> vT (B,NKV,64,S) bf16 -------
__global__ __launch_bounds__(256) void v_transpose_kernel(const float* __restrict__ qkv,
                                                          unsigned short* __restrict__ vt) {
  const size_t HALFQ = (size_t)MROWS * NQKV;
  __shared__ float tile[64][65];
  int bkv = blockIdx.x >> 5;              // 0..7 = b*NKV+kvh
  int b = bkv >> 2, kvh = bkv & 3;
  int s0 = (blockIdx.x & 31) * 64;
  int t = threadIdx.x;
  int sl = t >> 2, ds = (t & 3) * 16;
  const float* src = qkv + (size_t)(b * S_LEN + s0 + sl) * NQKV + 1280 + kvh * 64 + ds;
#pragma unroll
  for (int k = 0; k < 4; ++k) {
    float4 v = *reinterpret_cast<const float4*>(src + 4 * k);
    float4 v2 = *reinterpret_cast<const float4*>(src + HALFQ + 4 * k);
    tile[sl][ds + 4 * k + 0] = v.x + v2.x;
    tile[sl][ds + 4 * k + 1] = v.y + v2.y;
    tile[sl][ds + 4 * k + 2] = v.z + v2.z;
    tile[sl][ds + 4 * k + 3] = v.w + v2.w;
  }
  __syncthreads();
  int d = t >> 2, ssg = (t & 3) * 16;
  bf16x8 v0, v1;
#pragma unroll
  for (int i = 0; i < 8; ++i) v0[i] = (short)f2bf(tile[ssg + i][d]);
#pragma unroll
  for (int i = 0; i < 8; ++i) v1[i] = (short)f2bf(tile[ssg + 8 + i][d]);
  unsigned short* dst = vt + ((size_t)bkv * 64 + d) * S_LEN + s0 + ssg;
  *reinterpret_cast<bf16x8*>(dst) = v0;
  *reinterpret_cast<bf16x8*>(dst + 8) = v1;
}

// ------- causal flash attention: tile-paired + split-S(2), GQA-shared -------
// Each block: 4 waves = 4 q-heads of one kv group; processes q-tiles (63-p)
// and p sequentially (exactly 33 kbi total -> uniform work), and only its z
// half of each tile's key range (split-S). Fixed-max exp2 softmax: partials
// combine as O=O0+O1, l=l0+l1 (no max rebase). Writes fp32 (O,l) partials.
__global__ __launch_bounds__(256, 1) void attn_kernel(const unsigned short* __restrict__ qb,
                                                      const unsigned short* __restrict__ kbuf,
                                                      const unsigned short* __restrict__ vt,
                                                      float* __restrict__ Opart,
                                                      float* __restrict__ lpart) {
  __shared__ __align__(16) unsigned short PT[4][2][16][72];
  int z = blockIdx.x & 1;
  int bkv = (blockIdx.x >> 1) & 7;
  int p = blockIdx.x >> 4;                 // 0..31
  int b = bkv >> 2, kvh = bkv & 3;
  int w = threadIdx.x >> 6;                // head within kv group
  int h = kvh * 4 + w;
  int lane = threadIdx.x & 63;
  int quad = lane >> 4, l16 = lane & 15;
  const unsigned short* Q = qb + (size_t)(b * NH + h) * S_LEN * HD;
  const unsigned short* Kh = kbuf + (size_t)(b * NKV + kvh) * S_LEN * HD;
  const unsigned short* Vh = vt + (size_t)(b * NKV + kvh) * HD * S_LEN;
  float* Ozp = Opart + (size_t)z * BATCH * NH * S_LEN * HD;
  float* lzp = lpart + (size_t)z * BATCH * NH * S_LEN;

  bf16x8 ones;
#pragma unroll
  for (int i = 0; i < 8; ++i) ones[i] = (short)0x3F80;   // bf16 1.0

#pragma unroll
  for (int m = 0; m < 2; ++m) {
    int t32 = m ? p : (63 - p);            // pair sums to 33 kbi total
    int qa = t32 * 32 + l16;
    bf16x8 bqa0 = *reinterpret_cast<const bf16x8*>(Q + (size_t)qa * HD + quad * 8);
    bf16x8 bqa1 = *reinterpret_cast<const bf16x8*>(Q + (size_t)qa * HD + 32 + quad * 8);
    bf16x8 bqb0 = *reinterpret_cast<const bf16x8*>(Q + (size_t)(qa + 16) * HD + quad * 8);
    bf16x8 bqb1 = *reinterpret_cast<const bf16x8*>(Q + (size_t)(qa + 16) * HD + 32 + quad * 8);

    f32x4 ot[2][4];
#pragma unroll
    for (int gq = 0; gq < 2; ++gq)
#pragma unroll
      for (int i = 0; i < 4; ++i) ot[gq][i] = (f32x4){0.f, 0.f, 0.f, 0.f};
    f32x4 ol[2] = {(f32x4){0.f, 0.f, 0.f, 0.f}, (f32x4){0.f, 0.f, 0.f, 0.f}};

    int n = (t32 >> 1) + 1;                // kbi count for this tile
    int half = (n + 1) >> 1;
    int kb_lo = z ? half : 0;
    int kb_hi = z ? n : half;

    if (kb_lo < kb_hi) {
      bf16x8 kc0[4], kc1[4], vc0[4], vc1[4];
      {
        const unsigned short* kp = Kh + (size_t)(kb_lo * 64 + l16) * HD;
        const unsigned short* vp = Vh + (size_t)l16 * S_LEN + kb_lo * 64;
#pragma unroll
        for (int km = 0; km < 4; ++km) {
          kc0[km] = *reinterpret_cast<const bf16x8*>(kp + (size_t)(km * 16) * HD + quad * 8);
          kc1[km] = *reinterpret_cast<const bf16x8*>(kp + (size_t)(km * 16) * HD + 32 + quad * 8);
          vc0[km] = *reinterpret_cast<const bf16x8*>(vp + (size_t)(km * 16) * S_LEN + quad * 8);
          vc1[km] = *reinterpret_cast<const bf16x8*>(vp + (size_t)(km * 16) * S_LEN + 32 + quad * 8);
        }
      }
      for (int kbi = kb_lo; kbi < kb_hi; ++kbi) {
        int kbase = kbi << 6;
        bool diag = (kbi == n - 1);        // causal mask only on diagonal tile
        bool more = (kbi + 1 < kb_hi);
        bf16x8 kn0[4], kn1[4], vn0[4], vn1[4];
        if (more) {
          const unsigned short* kp = Kh + (size_t)(kbase + 64 + l16) * HD;
          const unsigned short* vp = Vh + (size_t)l16 * S_LEN + kbase + 64;
#pragma unroll
          for (int km = 0; km < 4; ++km) {
            kn0[km] = *reinterpret_cast<const bf16x8*>(kp + (size_t)(km * 16) * HD + quad * 8);
            kn1[km] = *reinterpret_cast<const bf16x8*>(kp + (size_t)(km * 16) * HD + 32 + quad * 8);
            vn0[km] = *reinterpret_cast<const bf16x8*>(vp + (size_t)(km * 16) * S_LEN + quad * 8);
            vn1[km] = *reinterpret_cast<const bf16x8*>(vp + (size_t)(km * 16) * S_LEN + 32 + quad * 8);
          }
        }
        f32x4 sa[4], sb[4];
#pragma unroll
        for (int km = 0; km < 4; ++km) {
          f32x4 s = {0.f, 0.f, 0.f, 0.f};
          s = __builtin_amdgcn_mfma_f32_16x16x32_bf16(kc0[km], bqa0, s, 0, 0, 0);
          s = __builtin_amdgcn_mfma_f32_16x16x32_bf16(kc1[km], bqa1, s, 0, 0, 0);
          sa[km] = s;
          f32x4 s2 = {0.f, 0.f, 0.f, 0.f};
          s2 = __builtin_amdgcn_mfma_f32_16x16x32_bf16(kc0[km], bqb0, s2, 0, 0, 0);
          s2 = __builtin_amdgcn_mfma_f32_16x16x32_bf16(kc1[km], bqb1, s2, 0, 0, 0);
          sb[km] = s2;
        }
        if (diag) {
#pragma unroll
          for (int km = 0; km < 4; ++km)
#pragma unroll
            for (int rg = 0; rg < 4; ++rg) {
              int key = kbase + km * 16 + quad * 4 + rg;
              if (key > qa) sa[km][rg] = -1e30f;
              if (key > qa + 16) sb[km][rg] = -1e30f;
            }
        }
#pragma unroll
        for (int km = 0; km < 4; ++km) {
          float a0 = exp2f(sa[km][0]), a1 = exp2f(sa[km][1]);
          float a2 = exp2f(sa[km][2]), a3 = exp2f(sa[km][3]);
          uint2 pw;
          pw.x = __builtin_amdgcn_perm(__float_as_uint(a1), __float_as_uint(a0), 0x07060302);
          pw.y = __builtin_amdgcn_perm(__float_as_uint(a3), __float_as_uint(a2), 0x07060302);
          *reinterpret_cast<uint2*>(&PT[w][0][l16][km * 16 + quad * 4]) = pw;
          float b0 = exp2f(sb[km][0]), b1 = exp2f(sb[km][1]);
          float b2 = exp2f(sb[km][2]), b3 = exp2f(sb[km][3]);
          uint2 qw;
          qw.x = __builtin_amdgcn_perm(__float_as_uint(b1), __float_as_uint(b0), 0x07060302);
          qw.y = __builtin_amdgcn_perm(__float_as_uint(b3), __float_as_uint(b2), 0x07060302);
          *reinterpret_cast<uint2*>(&PT[w][1][l16][km * 16 + quad * 4]) = qw;
        }
        bf16x8 pa0 = *reinterpret_cast<const bf16x8*>(&PT[w][0][l16][quad * 8]);
        bf16x8 pa1 = *reinterpret_cast<const bf16x8*>(&PT[w][0][l16][32 + quad * 8]);
        bf16x8 pb0 = *reinterpret_cast<const bf16x8*>(&PT[w][1][l16][quad * 8]);
        bf16x8 pb1 = *reinterpret_cast<const bf16x8*>(&PT[w][1][l16][32 + quad * 8]);
        ol[0] = __builtin_amdgcn_mfma_f32_16x16x32_bf16(ones, pa0, ol[0], 0, 0, 0);
        ol[0] = __builtin_amdgcn_mfma_f32_16x16x32_bf16(ones, pa1, ol[0], 0, 0, 0);
        ol[1] = __builtin_amdgcn_mfma_f32_16x16x32_bf16(ones, pb0, ol[1], 0, 0, 0);
        ol[1] = __builtin_amdgcn_mfma_f32_16x16x32_bf16(ones, pb1, ol[1], 0, 0, 0);
#pragma unroll
        for (int dm = 0; dm < 4; ++dm) {
          ot[0][dm] = __builtin_amdgcn_mfma_f32_16x16x32_bf16(vc0[dm], pa0, ot[0][dm], 0, 0, 0);
          ot[0][dm] = __builtin_amdgcn_mfma_f32_16x16x32_bf16(vc1[dm], pa1, ot[0][dm], 0, 0, 0);
          ot[1][dm] = __builtin_amdgcn_mfma_f32_16x16x32_bf16(vc0[dm], pb0, ot[1][dm], 0, 0, 0);
          ot[1][dm] = __builtin_amdgcn_mfma_f32_16x16x32_bf16(vc1[dm], pb1, ot[1][dm], 0, 0, 0);
        }
        if (more) {
#pragma unroll
          for (int km = 0; km < 4; ++km) {
            kc0[km] = kn0[km]; kc1[km] = kn1[km];
            vc0[km] = vn0[km]; vc1[km] = vn1[km];
          }
        }
      }
    }
    // write fp32 partials (zeros if this z had no work for this tile)
#pragma unroll
    for (int gq = 0; gq < 2; ++gq) {
      size_t base = ((size_t)(b * NH + h) * S_LEN + qa + gq * 16) * HD;
#pragma unroll
      for (int dm = 0; dm < 4; ++dm)
        *reinterpret_cast<f32x4*>(Ozp + base + dm * 16 + quad * 4) = ot[gq][dm];
    }
    if (quad == 0) {
      size_t lb = (size_t)(b * NH + h) * S_LEN + t32 * 32 + l16;
      lzp[lb] = ol[0][0];
      lzp[lb + 16] = ol[1][0];
    }
  }
}

// ------- combine split-S partials: ctx = (O0+O1)/(l0+l1), bf16 -------
__global__ __launch_bounds__(256) void attn_combine_kernel(const float* __restrict__ Opart,
                                                           const float* __restrict__ lpart,
                                                           unsigned short* __restrict__ ctx) {
  const size_t OZ = (size_t)BATCH * NH * S_LEN * HD;
  const size_t LZ = (size_t)BATCH * NH * S_LEN;
  int i4 = blockIdx.x * 256 + threadIdx.x;   // one f32x4 per thread
  size_t i = (size_t)i4 * 4;
  int row = i4 >> 4;                          // [b][h][q]
  float4 o0 = *reinterpret_cast<const float4*>(Opart + i);
  float4 o1 = *reinterpret_cast<const float4*>(Opart + OZ + i);
  float inv = 1.0f / (lpart[row] + lpart[LZ + row]);
  int b = row >> 15, h = (row >> 11) & 15, q = row & 2047;
  int d = (i4 & 15) * 4;
  s16x4 pv;
  pv[0] = (short)f2bf((o0.x + o1.x) * inv);
  pv[1] = (short)f2bf((o0.y + o1.y) * inv);
  pv[2] = (short)f2bf((o0.z + o1.z) * inv);
  pv[3] = (short)f2bf((o0.w + o1.w) * inv);
  *reinterpret_cast<s16x4*>(ctx + ((size_t)(b * S_LEN + q)) * DM + h * HD + d) = pv;
}

// ---------------- launch ----------------
extern "C" void kernel_launch(void* const* d_in, const int* in_sizes, int n_in,
                              void* d_out, int out_size, void* d_ws, size_t ws_size,
                              hipStream_t stream) {
  const float* x = (const float*)d_in[0];
  const float* Wq = (const float*)d_in[1];
  const float* Wkv = (const float*)d_in[2];
  const float* Wo = (const float*)d_in[3];
  const float* q_scale = (const float*)d_in[4];
  const float* k_scale = (const float*)d_in[5];
  float* out = (float*)d_out;

  char* ws = (char*)d_ws;
  size_t off = 0;
  auto alloc = [&](size_t bytes) {
    void* p = ws + off;
    off += (bytes + 255) & ~(size_t)255;
    return p;
  };
  unsigned short* xb = (unsigned short*)alloc((size_t)MROWS * DM * 2);
  unsigned short* wt1 = (unsigned short*)alloc((size_t)NQKV * DM * 2);   // [Wq^T ; Wkv^T]
  unsigned short* wot = (unsigned short*)alloc((size_t)DM * DM * 2);
  float* qkvp = (float*)alloc(2 * (size_t)MROWS * NQKV * 4);             // split-K partials
  unsigned short* qb = (unsigned short*)alloc((size_t)BATCH * NH * S_LEN * HD * 2);
  unsigned short* kbuf = (unsigned short*)alloc((size_t)BATCH * NKV * S_LEN * HD * 2);
  unsigned short* vt = (unsigned short*)alloc((size_t)BATCH * NKV * HD * S_LEN * 2);
  unsigned short* ctx = (unsigned short*)alloc((size_t)MROWS * DM * 2);
  float* Opart = (float*)alloc(2 * (size_t)BATCH * NH * S_LEN * HD * 4); // split-S partials
  float* lpart = (float*)alloc(2 * (size_t)BATCH * NH * S_LEN * 4);

  cvt_x_kernel<<<(MROWS * DM) / 1024, 256, 0, stream>>>(x, xb, MROWS * DM);
  transpose_cvt_kernel<<<dim3(16, 16), 256, 0, stream>>>(Wq, wt1, 1024, 1024);
  transpose_cvt_kernel<<<dim3(8, 16), 256, 0, stream>>>(Wkv, wt1 + 1024 * 1024, 1024, 512);
  transpose_cvt_kernel<<<dim3(16, 16), 256, 0, stream>>>(Wo, wot, 1024, 1024);

  gemm_bt_splitk<<<dim3(NQKV / 128, MROWS / 128, 2), 256, 0, stream>>>(xb, wt1, qkvp,
                                                                       MROWS, NQKV, 512, DM);

  norm_rope_kernel<<<(MROWS * 20) / 4, 256, 0, stream>>>(qkvp, q_scale, k_scale, qb, kbuf);
  v_transpose_kernel<<<256, 256, 0, stream>>>(qkvp, vt);

  attn_kernel<<<512, 256, 0, stream>>>(qb, kbuf, vt, Opart, lpart);
  attn_combine_kernel<<<(BATCH * NH * S_LEN * HD / 4) / 256, 256, 0, stream>>>(Opart, lpart, ctx);

  gemm_bt_n64<<<dim3(DM / 64, MROWS / 128), 256, 0, stream>>>(ctx, wot, out, MROWS, DM, DM);
}

// Round 8
// 198.749 us; speedup vs baseline: 1.2189x; 1.2189x over previous
//
#include <hip/hip_runtime.h>

#define S_LEN 2048
#define BATCH 2
#define DM    1024
#define NH    16
#define NKV   4
#define HD    64
#define MROWS (BATCH * S_LEN)   // 4096
#define NQKV  1536              // 1024 q + 512 kv

typedef __attribute__((ext_vector_type(8))) short bf16x8;
typedef __attribute__((ext_vector_type(4))) short s16x4;
typedef __attribute__((ext_vector_type(4))) float f32x4;

__device__ __forceinline__ unsigned short f2bf(float f) {
  unsigned int u = __float_as_uint(f);
  u += 0x7FFF + ((u >> 16) & 1);   // RNE
  return (unsigned short)(u >> 16);
}

__device__ __forceinline__ void gload_lds16(const unsigned short* g, unsigned short* l) {
  __builtin_amdgcn_global_load_lds((const __attribute__((address_space(1))) void*)g,
                                   (__attribute__((address_space(3))) void*)l, 16, 0, 0);
}

// ---------------- x -> bf16 ----------------
__global__ __launch_bounds__(256) void cvt_x_kernel(const float* __restrict__ x,
                                                    unsigned short* __restrict__ xb, int n) {
  int i = (blockIdx.x * 256 + threadIdx.x) * 4;
  if (i < n) {
    float4 v = *reinterpret_cast<const float4*>(x + i);
    xb[i + 0] = f2bf(v.x);
    xb[i + 1] = f2bf(v.y);
    xb[i + 2] = f2bf(v.z);
    xb[i + 3] = f2bf(v.w);
  }
}

// ------- all three W (RxC fp32) -> W^T (CxR bf16) in ONE launch -------
__global__ __launch_bounds__(256) void transpose_all_kernel(const float* __restrict__ Wq,
                                                            const float* __restrict__ Wkv,
                                                            const float* __restrict__ Wo,
                                                            unsigned short* __restrict__ wt1,
                                                            unsigned short* __restrict__ wot) {
  __shared__ float tile[64][65];
  int bid = blockIdx.x;
  const float* in;
  unsigned short* out;
  int R, C, bx, by;
  if (bid < 256) { in = Wq; out = wt1; R = 1024; C = 1024; bx = bid & 15; by = bid >> 4; }
  else if (bid < 384) { int k = bid - 256; in = Wkv; out = wt1 + 1024 * 1024; R = 1024; C = 512; bx = k & 7; by = k >> 3; }
  else { int k = bid - 384; in = Wo; out = wot; R = 1024; C = 1024; bx = k & 15; by = k >> 4; }
  int r0 = by * 64, c0 = bx * 64;
  int t = threadIdx.x;
  int rl = t >> 2, cs = (t & 3) * 16;
#pragma unroll
  for (int k = 0; k < 4; ++k) {
    float4 v = *reinterpret_cast<const float4*>(in + (size_t)(r0 + rl) * C + c0 + cs + 4 * k);
    tile[rl][cs + 4 * k + 0] = v.x;
    tile[rl][cs + 4 * k + 1] = v.y;
    tile[rl][cs + 4 * k + 2] = v.z;
    tile[rl][cs + 4 * k + 3] = v.w;
  }
  __syncthreads();
  int cl = t >> 2, rs = (t & 3) * 16;
  bf16x8 v0, v1;
#pragma unroll
  for (int i = 0; i < 8; ++i) v0[i] = (short)f2bf(tile[rs + i][cl]);
#pragma unroll
  for (int i = 0; i < 8; ++i) v1[i] = (short)f2bf(tile[rs + 8 + i][cl]);
  unsigned short* dst = out + (size_t)(c0 + cl) * R + r0 + rs;
  *reinterpret_cast<bf16x8*>(dst) = v0;
  *reinterpret_cast<bf16x8*>(dst + 8) = v1;
}

// ------- gemm1 FUSED: qkv = xb @ wt1^T, epilogue does RMSNorm+RoPE (q,k) -------
// 128x64 tile: each block's 64 columns = exactly one head.
// bx 0..15 -> q head; 16..19 -> k head (post-scaled 0.125*log2e); 20..23 -> v rows.
__global__ __launch_bounds__(256) void gemm1_fused(const unsigned short* __restrict__ A,
                                                   const unsigned short* __restrict__ BT,
                                                   const float* __restrict__ q_scale,
                                                   const float* __restrict__ k_scale,
                                                   unsigned short* __restrict__ qb,
                                                   unsigned short* __restrict__ kbuf,
                                                   unsigned short* __restrict__ vrow,
                                                   int K) {
  __shared__ __align__(16) unsigned short As[128 * 64];
  __shared__ __align__(16) unsigned short Bs[64 * 64];
  int bx = blockIdx.x;
  int row0 = blockIdx.y * 128, col0 = bx * 64;
  int t = threadIdx.x;
  int w = t >> 6, lane = t & 63, quad = lane >> 4, l16 = lane & 15;
  int srow = lane >> 3;
  int scol = (lane & 7) * 8;

  f32x4 acc[2][4];
#pragma unroll
  for (int i = 0; i < 2; ++i)
#pragma unroll
    for (int j = 0; j < 4; ++j) acc[i][j] = (f32x4){0.f, 0.f, 0.f, 0.f};

  for (int k0 = 0; k0 < K; k0 += 64) {
#pragma unroll
    for (int j = 0; j < 4; ++j)
      gload_lds16(A + (size_t)(row0 + w * 32 + j * 8 + srow) * K + k0 + scol,
                  &As[(w * 32 + j * 8) * 64]);
#pragma unroll
    for (int j = 0; j < 2; ++j)
      gload_lds16(BT + (size_t)(col0 + w * 16 + j * 8 + srow) * K + k0 + scol,
                  &Bs[(w * 16 + j * 8) * 64]);
    __syncthreads();
#pragma unroll
    for (int ks = 0; ks < 2; ++ks) {
      bf16x8 af[2], bfr[4];
#pragma unroll
      for (int i = 0; i < 2; ++i)
        af[i] = *reinterpret_cast<const bf16x8*>(&As[(w * 32 + i * 16 + l16) * 64 + ks * 32 + quad * 8]);
#pragma unroll
      for (int j = 0; j < 4; ++j)
        bfr[j] = *reinterpret_cast<const bf16x8*>(&Bs[(j * 16 + l16) * 64 + ks * 32 + quad * 8]);
#pragma unroll
      for (int i = 0; i < 2; ++i)
#pragma unroll
        for (int j = 0; j < 4; ++j)
          acc[i][j] = __builtin_amdgcn_mfma_f32_16x16x32_bf16(af[i], bfr[j], acc[i][j], 0, 0, 0);
    }
    __syncthreads();
  }

  if (bx < 20) {
    // RMSNorm + RoPE epilogue. cols: d = j*16 + l16 (head-local), rows = tokens.
    const float* scale = (bx < 16) ? q_scale : k_scale;
    float post = (bx < 16) ? 1.0f : 0.125f * 1.44269504088896f;
    float sc0 = scale[l16], sc1 = scale[16 + l16], sc2 = scale[32 + l16], sc3 = scale[48 + l16];
    float invf0 = exp2f((float)l16 * (-13.2877123795495f / 32.0f));        // 10000^(-d/32), d=l16
    float invf1 = exp2f((float)(l16 + 16) * (-13.2877123795495f / 32.0f)); // d=16+l16
#pragma unroll
    for (int i = 0; i < 2; ++i)
#pragma unroll
      for (int rg = 0; rg < 4; ++rg) {
        int row = row0 + w * 32 + i * 16 + quad * 4 + rg;
        int b = row >> 11, s = row & 2047;
        float v0 = acc[i][0][rg], v1 = acc[i][1][rg], v2 = acc[i][2][rg], v3 = acc[i][3][rg];
        float ss = v0 * v0 + v1 * v1 + v2 * v2 + v3 * v3;
        ss += __shfl_xor(ss, 1, 64);
        ss += __shfl_xor(ss, 2, 64);
        ss += __shfl_xor(ss, 4, 64);
        ss += __shfl_xor(ss, 8, 64);
        float inv_rms = 1.0f / sqrtf(ss * (1.0f / 64.0f) + 1e-5f);
        float n0 = v0 * inv_rms * sc0, n1 = v1 * inv_rms * sc1;
        float n2 = v2 * inv_rms * sc2, n3 = v3 * inv_rms * sc3;
        float f0 = (float)s * invf0, f1 = (float)s * invf1;
        float c0 = cosf(f0), s0 = sinf(f0), c1 = cosf(f1), s1 = sinf(f1);
        float o0 = (n0 * c0 - n2 * s0) * post;   // d = l16       (x1 half)
        float o1 = (n1 * c1 - n3 * s1) * post;   // d = 16+l16
        float o2 = (n0 * s0 + n2 * c0) * post;   // d = 32+l16    (x2 half)
        float o3 = (n1 * s1 + n3 * c1) * post;   // d = 48+l16
        unsigned short* dst = (bx < 16)
            ? qb + ((size_t)(b * NH + bx) * S_LEN + s) * HD
            : kbuf + ((size_t)(b * NKV + (bx - 16)) * S_LEN + s) * HD;
        dst[l16] = f2bf(o0);
        dst[16 + l16] = f2bf(o1);
        dst[32 + l16] = f2bf(o2);
        dst[48 + l16] = f2bf(o3);
      }
  } else {
    int kvh = bx - 20;
#pragma unroll
    for (int i = 0; i < 2; ++i)
#pragma unroll
      for (int rg = 0; rg < 4; ++rg) {
        int row = row0 + w * 32 + i * 16 + quad * 4 + rg;
        unsigned short* dst = vrow + (size_t)row * 256 + kvh * 64;
        dst[l16] = f2bf(acc[i][0][rg]);
        dst[16 + l16] = f2bf(acc[i][1][rg]);
        dst[32 + l16] = f2bf(acc[i][2][rg]);
        dst[48 + l16] = f2bf(acc[i][3][rg]);
      }
  }
}

// ------- vrow (b*S+s, kvh*64+d) bf16 -> vt (b*NKV+kvh, d, s) bf16 -------
__global__ __launch_bounds__(256) void v_transpose_bf16(const unsigned short* __restrict__ vrow,
                                                        unsigned short* __restrict__ vt) {
  __shared__ unsigned short tile[64][72];
  int bkv = blockIdx.x >> 5;
  int b = bkv >> 2, kvh = bkv & 3;
  int s0 = (blockIdx.x & 31) * 64;
  int t = threadIdx.x;
  int sl = t >> 2, part = (t & 3) * 16;
  const unsigned short* src = vrow + (size_t)(b * S_LEN + s0 + sl) * 256 + kvh * 64 + part;
  *reinterpret_cast<bf16x8*>(&tile[sl][part]) = *reinterpret_cast<const bf16x8*>(src);
  *reinterpret_cast<bf16x8*>(&tile[sl][part + 8]) = *reinterpret_cast<const bf16x8*>(src + 8);
  __syncthreads();
  int d = t >> 2, sc = (t & 3) * 16;
  bf16x8 a0, a1;
#pragma unroll
  for (int i = 0; i < 8; ++i) a0[i] = (short)tile[sc + i][d];
#pragma unroll
  for (int i = 0; i < 8; ++i) a1[i] = (short)tile[sc + 8 + i][d];
  unsigned short* dst = vt + ((size_t)bkv * 64 + d) * S_LEN + s0 + sc;
  *reinterpret_cast<bf16x8*>(dst) = a0;
  *reinterpret_cast<bf16x8*>(dst + 8) = a1;
}

// ------- causal flash attention (R6 form): GQA-shared blocks, reg prefetch -------
__global__ __launch_bounds__(256, 1) void attn_kernel(const unsigned short* __restrict__ qb,
                                                      const unsigned short* __restrict__ kbuf,
                                                      const unsigned short* __restrict__ vt,
                                                      unsigned short* __restrict__ ctx) {
  __shared__ __align__(16) unsigned short PT[4][2][16][72];
  int g = blockIdx.x >> 3;                 // 0..63 q-tile slot
  int bkv = blockIdx.x & 7;                // b*NKV + kvh
  int t32 = (g < 32) ? (63 - g) : (g - 32);  // complementary pairing
  int b = bkv >> 2, kvh = bkv & 3;
  int w = threadIdx.x >> 6;                // head within kv group
  int h = kvh * 4 + w;
  int lane = threadIdx.x & 63;
  int quad = lane >> 4, l16 = lane & 15;
  int qa = t32 * 32 + l16;                 // q-group a; group b = qa + 16
  const unsigned short* Q = qb + (size_t)(b * NH + h) * S_LEN * HD;
  const unsigned short* Kh = kbuf + (size_t)(b * NKV + kvh) * S_LEN * HD;
  const unsigned short* Vh = vt + (size_t)(b * NKV + kvh) * HD * S_LEN;

  bf16x8 bqa0 = *reinterpret_cast<const bf16x8*>(Q + (size_t)qa * HD + quad * 8);
  bf16x8 bqa1 = *reinterpret_cast<const bf16x8*>(Q + (size_t)qa * HD + 32 + quad * 8);
  bf16x8 bqb0 = *reinterpret_cast<const bf16x8*>(Q + (size_t)(qa + 16) * HD + quad * 8);
  bf16x8 bqb1 = *reinterpret_cast<const bf16x8*>(Q + (size_t)(qa + 16) * HD + 32 + quad * 8);

  bf16x8 ones;
#pragma unroll
  for (int i = 0; i < 8; ++i) ones[i] = (short)0x3F80;   // bf16 1.0

  f32x4 ot[2][4];
#pragma unroll
  for (int gq = 0; gq < 2; ++gq)
#pragma unroll
    for (int i = 0; i < 4; ++i) ot[gq][i] = (f32x4){0.f, 0.f, 0.f, 0.f};
  f32x4 ol[2] = {(f32x4){0.f, 0.f, 0.f, 0.f}, (f32x4){0.f, 0.f, 0.f, 0.f}};

  int nkb = (t32 >> 1) + 1;

  bf16x8 kc0[4], kc1[4], vc0[4], vc1[4];
#pragma unroll
  for (int km = 0; km < 4; ++km) {
    const unsigned short* kp = Kh + (size_t)(km * 16 + l16) * HD;
    kc0[km] = *reinterpret_cast<const bf16x8*>(kp + quad * 8);
    kc1[km] = *reinterpret_cast<const bf16x8*>(kp + 32 + quad * 8);
    const unsigned short* vp = Vh + (size_t)(km * 16 + l16) * S_LEN;
    vc0[km] = *reinterpret_cast<const bf16x8*>(vp + quad * 8);
    vc1[km] = *reinterpret_cast<const bf16x8*>(vp + 32 + quad * 8);
  }

  for (int kbi = 0; kbi < nkb; ++kbi) {
    bool last = (kbi == nkb - 1);
    int kbase = kbi << 6;
    bf16x8 kn0[4], kn1[4], vn0[4], vn1[4];
    if (!last) {
      const unsigned short* kp = Kh + (size_t)(kbase + 64 + l16) * HD;
      const unsigned short* vp = Vh + (size_t)l16 * S_LEN + kbase + 64;
#pragma unroll
      for (int km = 0; km < 4; ++km) {
        kn0[km] = *reinterpret_cast<const bf16x8*>(kp + (size_t)(km * 16) * HD + quad * 8);
        kn1[km] = *reinterpret_cast<const bf16x8*>(kp + (size_t)(km * 16) * HD + 32 + quad * 8);
        vn0[km] = *reinterpret_cast<const bf16x8*>(vp + (size_t)(km * 16) * S_LEN + quad * 8);
        vn1[km] = *reinterpret_cast<const bf16x8*>(vp + (size_t)(km * 16) * S_LEN + 32 + quad * 8);
      }
    }
    f32x4 sa[4], sb[4];
#pragma unroll
    for (int km = 0; km < 4; ++km) {
      f32x4 s = {0.f, 0.f, 0.f, 0.f};
      s = __builtin_amdgcn_mfma_f32_16x16x32_bf16(kc0[km], bqa0, s, 0, 0, 0);
      s = __builtin_amdgcn_mfma_f32_16x16x32_bf16(kc1[km], bqa1, s, 0, 0, 0);
      sa[km] = s;
      f32x4 s2 = {0.f, 0.f, 0.f, 0.f};
      s2 = __builtin_amdgcn_mfma_f32_16x16x32_bf16(kc0[km], bqb0, s2, 0, 0, 0);
      s2 = __builtin_amdgcn_mfma_f32_16x16x32_bf16(kc1[km], bqb1, s2, 0, 0, 0);
      sb[km] = s2;
    }
    if (last) {
#pragma unroll
      for (int km = 0; km < 4; ++km)
#pragma unroll
        for (int rg = 0; rg < 4; ++rg) {
          int key = kbase + km * 16 + quad * 4 + rg;
          if (key > qa) sa[km][rg] = -1e30f;
          if (key > qa + 16) sb[km][rg] = -1e30f;
        }
    }
#pragma unroll
    for (int km = 0; km < 4; ++km) {
      float a0 = exp2f(sa[km][0]), a1 = exp2f(sa[km][1]);
      float a2 = exp2f(sa[km][2]), a3 = exp2f(sa[km][3]);
      uint2 pw;
      pw.x = __builtin_amdgcn_perm(__float_as_uint(a1), __float_as_uint(a0), 0x07060302);
      pw.y = __builtin_amdgcn_perm(__float_as_uint(a3), __float_as_uint(a2), 0x07060302);
      *reinterpret_cast<uint2*>(&PT[w][0][l16][km * 16 + quad * 4]) = pw;
      float b0 = exp2f(sb[km][0]), b1 = exp2f(sb[km][1]);
      float b2 = exp2f(sb[km][2]), b3 = exp2f(sb[km][3]);
      uint2 qw;
      qw.x = __builtin_amdgcn_perm(__float_as_uint(b1), __float_as_uint(b0), 0x07060302);
      qw.y = __builtin_amdgcn_perm(__float_as_uint(b3), __float_as_uint(b2), 0x07060302);
      *reinterpret_cast<uint2*>(&PT[w][1][l16][km * 16 + quad * 4]) = qw;
    }
    bf16x8 pa0 = *reinterpret_cast<const bf16x8*>(&PT[w][0][l16][quad * 8]);
    bf16x8 pa1 = *reinterpret_cast<const bf16x8*>(&PT[w][0][l16][32 + quad * 8]);
    bf16x8 pb0 = *reinterpret_cast<const bf16x8*>(&PT[w][1][l16][quad * 8]);
    bf16x8 pb1 = *reinterpret_cast<const bf16x8*>(&PT[w][1][l16][32 + quad * 8]);
    ol[0] = __builtin_amdgcn_mfma_f32_16x16x32_bf16(ones, pa0, ol[0], 0, 0, 0);
    ol[0] = __builtin_amdgcn_mfma_f32_16x16x32_bf16(ones, pa1, ol[0], 0, 0, 0);
    ol[1] = __builtin_amdgcn_mfma_f32_16x16x32_bf16(ones, pb0, ol[1], 0, 0, 0);
    ol[1] = __builtin_amdgcn_mfma_f32_16x16x32_bf16(ones, pb1, ol[1], 0, 0, 0);
#pragma unroll
    for (int dm = 0; dm < 4; ++dm) {
      ot[0][dm] = __builtin_amdgcn_mfma_f32_16x16x32_bf16(vc0[dm], pa0, ot[0][dm], 0, 0, 0);
      ot[0][dm] = __builtin_amdgcn_mfma_f32_16x16x32_bf16(vc1[dm], pa1, ot[0][dm], 0, 0, 0);
      ot[1][dm] = __builtin_amdgcn_mfma_f32_16x16x32_bf16(vc0[dm], pb0, ot[1][dm], 0, 0, 0);
      ot[1][dm] = __builtin_amdgcn_mfma_f32_16x16x32_bf16(vc1[dm], pb1, ot[1][dm], 0, 0, 0);
    }
    if (!last) {
#pragma unroll
      for (int km = 0; km < 4; ++km) {
        kc0[km] = kn0[km]; kc1[km] = kn1[km];
        vc0[km] = vn0[km]; vc1[km] = vn1[km];
      }
    }
  }

#pragma unroll
  for (int gq = 0; gq < 2; ++gq) {
    float inv_l = 1.0f / ol[gq][0];
    size_t base = ((size_t)(b * S_LEN) + qa + gq * 16) * DM + h * HD;
#pragma unroll
    for (int dm = 0; dm < 4; ++dm) {
      s16x4 pv;
#pragma unroll
      for (int rg = 0; rg < 4; ++rg) pv[rg] = (short)f2bf(ot[gq][dm][rg] * inv_l);
      *reinterpret_cast<s16x4*>(ctx + base + dm * 16 + quad * 4) = pv;
    }
  }
}

// ------- gemm2: out = ctx @ wot^T, 128x64 tile, direct fp32 C -------
__global__ __launch_bounds__(256) void gemm_bt_n64(const unsigned short* __restrict__ A,
                                                   const unsigned short* __restrict__ BT,
                                                   float* __restrict__ C,
                                                   int M, int N, int K) {
  __shared__ __align__(16) unsigned short As[128 * 64];
  __shared__ __align__(16) unsigned short Bs[64 * 64];
  int row0 = blockIdx.y * 128, col0 = blockIdx.x * 64;
  int t = threadIdx.x;
  int w = t >> 6, lane = t & 63, quad = lane >> 4, l16 = lane & 15;
  int srow = lane >> 3;
  int scol = (lane & 7) * 8;

  f32x4 acc[2][4];
#pragma unroll
  for (int i = 0; i < 2; ++i)
#pragma unroll
    for (int j = 0; j < 4; ++j) acc[i][j] = (f32x4){0.f, 0.f, 0.f, 0.f};

  for (int k0 = 0; k0 < K; k0 += 64) {
#pragma unroll
    for (int j = 0; j < 4; ++j)
      gload_lds16(A + (size_t)(row0 + w * 32 + j * 8 + srow) * K + k0 + scol,
                  &As[(w * 32 + j * 8) * 64]);
#pragma unroll
    for (int j = 0; j < 2; ++j)
      gload_lds16(BT + (size_t)(col0 + w * 16 + j * 8 + srow) * K + k0 + scol,
                  &Bs[(w * 16 + j * 8) * 64]);
    __syncthreads();
#pragma unroll
    for (int ks = 0; ks < 2; ++ks) {
      bf16x8 af[2], bfr[4];
#pragma unroll
      for (int i = 0; i < 2; ++i)
        af[i] = *reinterpret_cast<const bf16x8*>(&As[(w * 32 + i * 16 + l16) * 64 + ks * 32 + quad * 8]);
#pragma unroll
      for (int j = 0; j < 4; ++j)
        bfr[j] = *reinterpret_cast<const bf16x8*>(&Bs[(j * 16 + l16) * 64 + ks * 32 + quad * 8]);
#pragma unroll
      for (int i = 0; i < 2; ++i)
#pragma unroll
        for (int j = 0; j < 4; ++j)
          acc[i][j] = __builtin_amdgcn_mfma_f32_16x16x32_bf16(af[i], bfr[j], acc[i][j], 0, 0, 0);
    }
    __syncthreads();
  }
#pragma unroll
  for (int i = 0; i < 2; ++i)
#pragma unroll
    for (int j = 0; j < 4; ++j) {
      int row = row0 + w * 32 + i * 16 + quad * 4;
      float* Cptr = C + (size_t)row * N + col0 + j * 16 + l16;
#pragma unroll
      for (int rg = 0; rg < 4; ++rg) Cptr[(size_t)rg * N] = acc[i][j][rg];
    }
}

// ---------------- launch ----------------
extern "C" void kernel_launch(void* const* d_in, const int* in_sizes, int n_in,
                              void* d_out, int out_size, void* d_ws, size_t ws_size,
                              hipStream_t stream) {
  const float* x = (const float*)d_in[0];
  const float* Wq = (const float*)d_in[1];
  const float* Wkv = (const float*)d_in[2];
  const float* Wo = (const float*)d_in[3];
  const float* q_scale = (const float*)d_in[4];
  const float* k_scale = (const float*)d_in[5];
  float* out = (float*)d_out;

  char* ws = (char*)d_ws;
  size_t off = 0;
  auto alloc = [&](size_t bytes) {
    void* p = ws + off;
    off += (bytes + 255) & ~(size_t)255;
    return p;
  };
  unsigned short* xb = (unsigned short*)alloc((size_t)MROWS * DM * 2);
  unsigned short* wt1 = (unsigned short*)alloc((size_t)NQKV * DM * 2);   // [Wq^T ; Wkv^T]
  unsigned short* wot = (unsigned short*)alloc((size_t)DM * DM * 2);
  unsigned short* qb = (unsigned short*)alloc((size_t)BATCH * NH * S_LEN * HD * 2);
  unsigned short* kbuf = (unsigned short*)alloc((size_t)BATCH * NKV * S_LEN * HD * 2);
  unsigned short* vrow = (unsigned short*)alloc((size_t)MROWS * NKV * HD * 2);
  unsigned short* vt = (unsigned short*)alloc((size_t)BATCH * NKV * HD * S_LEN * 2);
  unsigned short* ctx = (unsigned short*)alloc((size_t)MROWS * DM * 2);

  cvt_x_kernel<<<(MROWS * DM) / 1024, 256, 0, stream>>>(x, xb, MROWS * DM);
  transpose_all_kernel<<<640, 256, 0, stream>>>(Wq, Wkv, Wo, wt1, wot);

  gemm1_fused<<<dim3(NQKV / 64, MROWS / 128), 256, 0, stream>>>(xb, wt1, q_scale, k_scale,
                                                                qb, kbuf, vrow, DM);
  v_transpose_bf16<<<256, 256, 0, stream>>>(vrow, vt);

  attn_kernel<<<BATCH * NKV * (S_LEN / 32), 256, 0, stream>>>(qb, kbuf, vt, ctx);

  gemm_bt_n64<<<dim3(DM / 64, MROWS / 128), 256, 0, stream>>>(ctx, wot, out, MROWS, DM, DM);
}

// Round 9
// 190.649 us; speedup vs baseline: 1.2707x; 1.0425x over previous
//
#include <hip/hip_runtime.h>

#define S_LEN 2048
#define BATCH 2
#define DM    1024
#define NH    16
#define NKV   4
#define HD    64
#define MROWS (BATCH * S_LEN)   // 4096
#define NQKV  1536              // 1024 q + 512 kv

typedef __attribute__((ext_vector_type(8))) short bf16x8;
typedef __attribute__((ext_vector_type(4))) short s16x4;
typedef __attribute__((ext_vector_type(4))) float f32x4;

__device__ __forceinline__ unsigned short f2bf(float f) {
  unsigned int u = __float_as_uint(f);
  u += 0x7FFF + ((u >> 16) & 1);   // RNE
  return (unsigned short)(u >> 16);
}

__device__ __forceinline__ void gload_lds16(const unsigned short* g, unsigned short* l) {
  __builtin_amdgcn_global_load_lds((const __attribute__((address_space(1))) void*)g,
                                   (__attribute__((address_space(3))) void*)l, 16, 0, 0);
}
__device__ __forceinline__ void gload_lds4(const unsigned short* g, unsigned short* l) {
  __builtin_amdgcn_global_load_lds((const __attribute__((address_space(1))) void*)g,
                                   (__attribute__((address_space(3))) void*)l, 4, 0, 0);
}

// ---------------- x -> bf16 ----------------
__global__ __launch_bounds__(256) void cvt_x_kernel(const float* __restrict__ x,
                                                    unsigned short* __restrict__ xb, int n) {
  int i = (blockIdx.x * 256 + threadIdx.x) * 4;
  if (i < n) {
    float4 v = *reinterpret_cast<const float4*>(x + i);
    xb[i + 0] = f2bf(v.x);
    xb[i + 1] = f2bf(v.y);
    xb[i + 2] = f2bf(v.z);
    xb[i + 3] = f2bf(v.w);
  }
}

// ------- all three W (RxC fp32) -> W^T (CxR bf16) in ONE launch -------
__global__ __launch_bounds__(256) void transpose_all_kernel(const float* __restrict__ Wq,
                                                            const float* __restrict__ Wkv,
                                                            const float* __restrict__ Wo,
                                                            unsigned short* __restrict__ wt1,
                                                            unsigned short* __restrict__ wot) {
  __shared__ float tile[64][65];
  int bid = blockIdx.x;
  const float* in;
  unsigned short* out;
  int R, C, bx, by;
  if (bid < 256) { in = Wq; out = wt1; R = 1024; C = 1024; bx = bid & 15; by = bid >> 4; }
  else if (bid < 384) { int k = bid - 256; in = Wkv; out = wt1 + 1024 * 1024; R = 1024; C = 512; bx = k & 7; by = k >> 3; }
  else { int k = bid - 384; in = Wo; out = wot; R = 1024; C = 1024; bx = k & 15; by = k >> 4; }
  int r0 = by * 64, c0 = bx * 64;
  int t = threadIdx.x;
  int rl = t >> 2, cs = (t & 3) * 16;
#pragma unroll
  for (int k = 0; k < 4; ++k) {
    float4 v = *reinterpret_cast<const float4*>(in + (size_t)(r0 + rl) * C + c0 + cs + 4 * k);
    tile[rl][cs + 4 * k + 0] = v.x;
    tile[rl][cs + 4 * k + 1] = v.y;
    tile[rl][cs + 4 * k + 2] = v.z;
    tile[rl][cs + 4 * k + 3] = v.w;
  }
  __syncthreads();
  int cl = t >> 2, rs = (t & 3) * 16;
  bf16x8 v0, v1;
#pragma unroll
  for (int i = 0; i < 8; ++i) v0[i] = (short)f2bf(tile[rs + i][cl]);
#pragma unroll
  for (int i = 0; i < 8; ++i) v1[i] = (short)f2bf(tile[rs + 8 + i][cl]);
  unsigned short* dst = out + (size_t)(c0 + cl) * R + r0 + rs;
  *reinterpret_cast<bf16x8*>(dst) = v0;
  *reinterpret_cast<bf16x8*>(dst + 8) = v1;
}

// ------- gemm1 FUSED: qkv = xb @ wt1^T, epilogue does RMSNorm+RoPE (q,k) -------
__global__ __launch_bounds__(256) void gemm1_fused(const unsigned short* __restrict__ A,
                                                   const unsigned short* __restrict__ BT,
                                                   const float* __restrict__ q_scale,
                                                   const float* __restrict__ k_scale,
                                                   unsigned short* __restrict__ qb,
                                                   unsigned short* __restrict__ kbuf,
                                                   unsigned short* __restrict__ vrow,
                                                   int K) {
  __shared__ __align__(16) unsigned short As[128 * 64];
  __shared__ __align__(16) unsigned short Bs[64 * 64];
  int bx = blockIdx.x;
  int row0 = blockIdx.y * 128, col0 = bx * 64;
  int t = threadIdx.x;
  int w = t >> 6, lane = t & 63, quad = lane >> 4, l16 = lane & 15;
  int srow = lane >> 3;
  int scol = (lane & 7) * 8;

  f32x4 acc[2][4];
#pragma unroll
  for (int i = 0; i < 2; ++i)
#pragma unroll
    for (int j = 0; j < 4; ++j) acc[i][j] = (f32x4){0.f, 0.f, 0.f, 0.f};

  for (int k0 = 0; k0 < K; k0 += 64) {
#pragma unroll
    for (int j = 0; j < 4; ++j)
      gload_lds16(A + (size_t)(row0 + w * 32 + j * 8 + srow) * K + k0 + scol,
                  &As[(w * 32 + j * 8) * 64]);
#pragma unroll
    for (int j = 0; j < 2; ++j)
      gload_lds16(BT + (size_t)(col0 + w * 16 + j * 8 + srow) * K + k0 + scol,
                  &Bs[(w * 16 + j * 8) * 64]);
    __syncthreads();
#pragma unroll
    for (int ks = 0; ks < 2; ++ks) {
      bf16x8 af[2], bfr[4];
#pragma unroll
      for (int i = 0; i < 2; ++i)
        af[i] = *reinterpret_cast<const bf16x8*>(&As[(w * 32 + i * 16 + l16) * 64 + ks * 32 + quad * 8]);
#pragma unroll
      for (int j = 0; j < 4; ++j)
        bfr[j] = *reinterpret_cast<const bf16x8*>(&Bs[(j * 16 + l16) * 64 + ks * 32 + quad * 8]);
#pragma unroll
      for (int i = 0; i < 2; ++i)
#pragma unroll
        for (int j = 0; j < 4; ++j)
          acc[i][j] = __builtin_amdgcn_mfma_f32_16x16x32_bf16(af[i], bfr[j], acc[i][j], 0, 0, 0);
    }
    __syncthreads();
  }

  if (bx < 20) {
    const float* scale = (bx < 16) ? q_scale : k_scale;
    float post = (bx < 16) ? 1.0f : 0.125f * 1.44269504088896f;
    float sc0 = scale[l16], sc1 = scale[16 + l16], sc2 = scale[32 + l16], sc3 = scale[48 + l16];
    float invf0 = exp2f((float)l16 * (-13.2877123795495f / 32.0f));
    float invf1 = exp2f((float)(l16 + 16) * (-13.2877123795495f / 32.0f));
#pragma unroll
    for (int i = 0; i < 2; ++i)
#pragma unroll
      for (int rg = 0; rg < 4; ++rg) {
        int row = row0 + w * 32 + i * 16 + quad * 4 + rg;
        int b = row >> 11, s = row & 2047;
        float v0 = acc[i][0][rg], v1 = acc[i][1][rg], v2 = acc[i][2][rg], v3 = acc[i][3][rg];
        float ss = v0 * v0 + v1 * v1 + v2 * v2 + v3 * v3;
        ss += __shfl_xor(ss, 1, 64);
        ss += __shfl_xor(ss, 2, 64);
        ss += __shfl_xor(ss, 4, 64);
        ss += __shfl_xor(ss, 8, 64);
        float inv_rms = 1.0f / sqrtf(ss * (1.0f / 64.0f) + 1e-5f);
        float n0 = v0 * inv_rms * sc0, n1 = v1 * inv_rms * sc1;
        float n2 = v2 * inv_rms * sc2, n3 = v3 * inv_rms * sc3;
        float f0 = (float)s * invf0, f1 = (float)s * invf1;
        float c0 = cosf(f0), s0 = sinf(f0), c1 = cosf(f1), s1 = sinf(f1);
        float o0 = (n0 * c0 - n2 * s0) * post;
        float o1 = (n1 * c1 - n3 * s1) * post;
        float o2 = (n0 * s0 + n2 * c0) * post;
        float o3 = (n1 * s1 + n3 * c1) * post;
        unsigned short* dst = (bx < 16)
            ? qb + ((size_t)(b * NH + bx) * S_LEN + s) * HD
            : kbuf + ((size_t)(b * NKV + (bx - 16)) * S_LEN + s) * HD;
        dst[l16] = f2bf(o0);
        dst[16 + l16] = f2bf(o1);
        dst[32 + l16] = f2bf(o2);
        dst[48 + l16] = f2bf(o3);
      }
  } else {
    int kvh = bx - 20;
#pragma unroll
    for (int i = 0; i < 2; ++i)
#pragma unroll
      for (int rg = 0; rg < 4; ++rg) {
        int row = row0 + w * 32 + i * 16 + quad * 4 + rg;
        unsigned short* dst = vrow + (size_t)row * 256 + kvh * 64;
        dst[l16] = f2bf(acc[i][0][rg]);
        dst[16 + l16] = f2bf(acc[i][1][rg]);
        dst[32 + l16] = f2bf(acc[i][2][rg]);
        dst[48 + l16] = f2bf(acc[i][3][rg]);
      }
  }
}

// ------- vrow (b*S+s, kvh*64+d) bf16 -> vt (b*NKV+kvh, d, s) bf16 -------
__global__ __launch_bounds__(256) void v_transpose_bf16(const unsigned short* __restrict__ vrow,
                                                        unsigned short* __restrict__ vt) {
  __shared__ unsigned short tile[64][72];
  int bkv = blockIdx.x >> 5;
  int b = bkv >> 2, kvh = bkv & 3;
  int s0 = (blockIdx.x & 31) * 64;
  int t = threadIdx.x;
  int sl = t >> 2, part = (t & 3) * 16;
  const unsigned short* src = vrow + (size_t)(b * S_LEN + s0 + sl) * 256 + kvh * 64 + part;
  *reinterpret_cast<bf16x8*>(&tile[sl][part]) = *reinterpret_cast<const bf16x8*>(src);
  *reinterpret_cast<bf16x8*>(&tile[sl][part + 8]) = *reinterpret_cast<const bf16x8*>(src + 8);
  __syncthreads();
  int d = t >> 2, sc = (t & 3) * 16;
  bf16x8 a0, a1;
#pragma unroll
  for (int i = 0; i < 8; ++i) a0[i] = (short)tile[sc + i][d];
#pragma unroll
  for (int i = 0; i < 8; ++i) a1[i] = (short)tile[sc + 8 + i][d];
  unsigned short* dst = vt + ((size_t)bkv * 64 + d) * S_LEN + s0 + sc;
  *reinterpret_cast<bf16x8*>(dst) = a0;
  *reinterpret_cast<bf16x8*>(dst + 8) = a1;
}

// ------- causal flash attention: GQA-shared, double-buffered LDS staging -------
// K/V tiles stream via async global_load_lds (width=4, 2-row chunks padded +16B
// -> ds_read_b128 fragments hit the bank floor). Prefetch for tile i+1 issues at
// the top of iter i; the vmcnt drain at the end-of-iter barrier lands a full
// compute phase after issue, so L2 latency is hidden regardless of VGPR budget.
#define CH 136                 // shorts per chunk: 256B data + 16B pad
#define TILE_SH (32 * CH)      // 32 chunks per 64-row tile
__global__ __launch_bounds__(256, 2) void attn_kernel(const unsigned short* __restrict__ qb,
                                                      const unsigned short* __restrict__ kbuf,
                                                      const unsigned short* __restrict__ vt,
                                                      unsigned short* __restrict__ ctx) {
  __shared__ __align__(16) unsigned short Ks[2][TILE_SH];
  __shared__ __align__(16) unsigned short Vs[2][TILE_SH];
  __shared__ __align__(16) unsigned short PT[4][2][16][72];
  int g = blockIdx.x >> 3;                 // 0..63 q-tile slot
  int bkv = blockIdx.x & 7;                // b*NKV + kvh
  int t32 = (g < 32) ? (63 - g) : (g - 32);  // complementary pairing
  int b = bkv >> 2, kvh = bkv & 3;
  int w = threadIdx.x >> 6;                // head within kv group
  int h = kvh * 4 + w;
  int lane = threadIdx.x & 63;
  int quad = lane >> 4, l16 = lane & 15;
  int qa = t32 * 32 + l16;                 // q-group a; group b = qa + 16
  const unsigned short* Q = qb + (size_t)(b * NH + h) * S_LEN * HD;
  const unsigned short* Kh = kbuf + (size_t)(b * NKV + kvh) * S_LEN * HD;
  const unsigned short* Vh = vt + (size_t)(b * NKV + kvh) * HD * S_LEN;

  bf16x8 bqa0 = *reinterpret_cast<const bf16x8*>(Q + (size_t)qa * HD + quad * 8);
  bf16x8 bqa1 = *reinterpret_cast<const bf16x8*>(Q + (size_t)qa * HD + 32 + quad * 8);
  bf16x8 bqb0 = *reinterpret_cast<const bf16x8*>(Q + (size_t)(qa + 16) * HD + quad * 8);
  bf16x8 bqb1 = *reinterpret_cast<const bf16x8*>(Q + (size_t)(qa + 16) * HD + 32 + quad * 8);

  bf16x8 ones;
#pragma unroll
  for (int i = 0; i < 8; ++i) ones[i] = (short)0x3F80;   // bf16 1.0

  f32x4 ot[2][4];
#pragma unroll
  for (int gq = 0; gq < 2; ++gq)
#pragma unroll
    for (int i = 0; i < 4; ++i) ot[gq][i] = (f32x4){0.f, 0.f, 0.f, 0.f};
  f32x4 ol[2] = {(f32x4){0.f, 0.f, 0.f, 0.f}, (f32x4){0.f, 0.f, 0.f, 0.f}};

  int nkb = (t32 >> 1) + 1;

  // stage: wave w loads K chunks [8w,8w+8) and V chunks [8w,8w+8) of one tile.
  // K chunk c' = keys (2c',2c'+1) x dims 0..63; V chunk c' = dims (2c',2c'+1) x keys 0..63.
  auto stage = [&](int kbase, int dbuf) {
    const unsigned short* kg = Kh + (size_t)(kbase + w * 16) * HD + lane * 2;
    const unsigned short* vg = Vh + (size_t)(w * 16 + (lane >> 5)) * S_LEN + kbase + (lane & 31) * 2;
    unsigned short* kl = &Ks[dbuf][(w * 8) * CH];
    unsigned short* vl = &Vs[dbuf][(w * 8) * CH];
#pragma unroll
    for (int c = 0; c < 8; ++c) {
      gload_lds4(kg + (size_t)(2 * c) * HD, kl + c * CH);
      gload_lds4(vg + (size_t)(2 * c) * S_LEN, vl + c * CH);
    }
  };

  stage(0, 0);
  __syncthreads();

  for (int kbi = 0; kbi < nkb; ++kbi) {
    bool last = (kbi == nkb - 1);
    int kbase = kbi << 6;
    if (!last) stage(kbase + 64, (kbi + 1) & 1);
    const unsigned short* Kd = Ks[kbi & 1];
    const unsigned short* Vd = Vs[kbi & 1];

    f32x4 sa[4], sb[4];
#pragma unroll
    for (int km = 0; km < 4; ++km) {
      int ch = km * 8 + (l16 >> 1);
      int base = ch * CH + (l16 & 1) * 64;
      bf16x8 k0 = *reinterpret_cast<const bf16x8*>(&Kd[base + quad * 8]);
      bf16x8 k1 = *reinterpret_cast<const bf16x8*>(&Kd[base + 32 + quad * 8]);
      f32x4 s = {0.f, 0.f, 0.f, 0.f};
      s = __builtin_amdgcn_mfma_f32_16x16x32_bf16(k0, bqa0, s, 0, 0, 0);
      s = __builtin_amdgcn_mfma_f32_16x16x32_bf16(k1, bqa1, s, 0, 0, 0);
      sa[km] = s;
      f32x4 s2 = {0.f, 0.f, 0.f, 0.f};
      s2 = __builtin_amdgcn_mfma_f32_16x16x32_bf16(k0, bqb0, s2, 0, 0, 0);
      s2 = __builtin_amdgcn_mfma_f32_16x16x32_bf16(k1, bqb1, s2, 0, 0, 0);
      sb[km] = s2;
    }
    if (last) {
#pragma unroll
      for (int km = 0; km < 4; ++km)
#pragma unroll
        for (int rg = 0; rg < 4; ++rg) {
          int key = kbase + km * 16 + quad * 4 + rg;
          if (key > qa) sa[km][rg] = -1e30f;
          if (key > qa + 16) sb[km][rg] = -1e30f;
        }
    }
#pragma unroll
    for (int km = 0; km < 4; ++km) {
      float a0 = exp2f(sa[km][0]), a1 = exp2f(sa[km][1]);
      float a2 = exp2f(sa[km][2]), a3 = exp2f(sa[km][3]);
      uint2 pw;
      pw.x = __builtin_amdgcn_perm(__float_as_uint(a1), __float_as_uint(a0), 0x07060302);
      pw.y = __builtin_amdgcn_perm(__float_as_uint(a3), __float_as_uint(a2), 0x07060302);
      *reinterpret_cast<uint2*>(&PT[w][0][l16][km * 16 + quad * 4]) = pw;
      float b0 = exp2f(sb[km][0]), b1 = exp2f(sb[km][1]);
      float b2 = exp2f(sb[km][2]), b3 = exp2f(sb[km][3]);
      uint2 qw;
      qw.x = __builtin_amdgcn_perm(__float_as_uint(b1), __float_as_uint(b0), 0x07060302);
      qw.y = __builtin_amdgcn_perm(__float_as_uint(b3), __float_as_uint(b2), 0x07060302);
      *reinterpret_cast<uint2*>(&PT[w][1][l16][km * 16 + quad * 4]) = qw;
    }
    bf16x8 pa0 = *reinterpret_cast<const bf16x8*>(&PT[w][0][l16][quad * 8]);
    bf16x8 pa1 = *reinterpret_cast<const bf16x8*>(&PT[w][0][l16][32 + quad * 8]);
    bf16x8 pb0 = *reinterpret_cast<const bf16x8*>(&PT[w][1][l16][quad * 8]);
    bf16x8 pb1 = *reinterpret_cast<const bf16x8*>(&PT[w][1][l16][32 + quad * 8]);
    ol[0] = __builtin_amdgcn_mfma_f32_16x16x32_bf16(ones, pa0, ol[0], 0, 0, 0);
    ol[0] = __builtin_amdgcn_mfma_f32_16x16x32_bf16(ones, pa1, ol[0], 0, 0, 0);
    ol[1] = __builtin_amdgcn_mfma_f32_16x16x32_bf16(ones, pb0, ol[1], 0, 0, 0);
    ol[1] = __builtin_amdgcn_mfma_f32_16x16x32_bf16(ones, pb1, ol[1], 0, 0, 0);
#pragma unroll
    for (int dm = 0; dm < 4; ++dm) {
      int ch = dm * 8 + (l16 >> 1);
      int base = ch * CH + (l16 & 1) * 64;
      bf16x8 v0 = *reinterpret_cast<const bf16x8*>(&Vd[base + quad * 8]);
      bf16x8 v1 = *reinterpret_cast<const bf16x8*>(&Vd[base + 32 + quad * 8]);
      ot[0][dm] = __builtin_amdgcn_mfma_f32_16x16x32_bf16(v0, pa0, ot[0][dm], 0, 0, 0);
      ot[0][dm] = __builtin_amdgcn_mfma_f32_16x16x32_bf16(v1, pa1, ot[0][dm], 0, 0, 0);
      ot[1][dm] = __builtin_amdgcn_mfma_f32_16x16x32_bf16(v0, pb0, ot[1][dm], 0, 0, 0);
      ot[1][dm] = __builtin_amdgcn_mfma_f32_16x16x32_bf16(v1, pb1, ot[1][dm], 0, 0, 0);
    }
    __syncthreads();   // drains next-tile prefetch (issued a full phase ago) + buffer swap
  }

#pragma unroll
  for (int gq = 0; gq < 2; ++gq) {
    float inv_l = 1.0f / ol[gq][0];
    size_t base = ((size_t)(b * S_LEN) + qa + gq * 16) * DM + h * HD;
#pragma unroll
    for (int dm = 0; dm < 4; ++dm) {
      s16x4 pv;
#pragma unroll
      for (int rg = 0; rg < 4; ++rg) pv[rg] = (short)f2bf(ot[gq][dm][rg] * inv_l);
      *reinterpret_cast<s16x4*>(ctx + base + dm * 16 + quad * 4) = pv;
    }
  }
}

// ------- gemm2: out = ctx @ wot^T, 128x64 tile, direct fp32 C -------
__global__ __launch_bounds__(256) void gemm_bt_n64(const unsigned short* __restrict__ A,
                                                   const unsigned short* __restrict__ BT,
                                                   float* __restrict__ C,
                                                   int M, int N, int K) {
  __shared__ __align__(16) unsigned short As[128 * 64];
  __shared__ __align__(16) unsigned short Bs[64 * 64];
  int row0 = blockIdx.y * 128, col0 = blockIdx.x * 64;
  int t = threadIdx.x;
  int w = t >> 6, lane = t & 63, quad = lane >> 4, l16 = lane & 15;
  int srow = lane >> 3;
  int scol = (lane & 7) * 8;

  f32x4 acc[2][4];
#pragma unroll
  for (int i = 0; i < 2; ++i)
#pragma unroll
    for (int j = 0; j < 4; ++j) acc[i][j] = (f32x4){0.f, 0.f, 0.f, 0.f};

  for (int k0 = 0; k0 < K; k0 += 64) {
#pragma unroll
    for (int j = 0; j < 4; ++j)
      gload_lds16(A + (size_t)(row0 + w * 32 + j * 8 + srow) * K + k0 + scol,
                  &As[(w * 32 + j * 8) * 64]);
#pragma unroll
    for (int j = 0; j < 2; ++j)
      gload_lds16(BT + (size_t)(col0 + w * 16 + j * 8 + srow) * K + k0 + scol,
                  &Bs[(w * 16 + j * 8) * 64]);
    __syncthreads();
#pragma unroll
    for (int ks = 0; ks < 2; ++ks) {
      bf16x8 af[2], bfr[4];
#pragma unroll
      for (int i = 0; i < 2; ++i)
        af[i] = *reinterpret_cast<const bf16x8*>(&As[(w * 32 + i * 16 + l16) * 64 + ks * 32 + quad * 8]);
#pragma unroll
      for (int j = 0; j < 4; ++j)
        bfr[j] = *reinterpret_cast<const bf16x8*>(&Bs[(j * 16 + l16) * 64 + ks * 32 + quad * 8]);
#pragma unroll
      for (int i = 0; i < 2; ++i)
#pragma unroll
        for (int j = 0; j < 4; ++j)
          acc[i][j] = __builtin_amdgcn_mfma_f32_16x16x32_bf16(af[i], bfr[j], acc[i][j], 0, 0, 0);
    }
    __syncthreads();
  }
#pragma unroll
  for (int i = 0; i < 2; ++i)
#pragma unroll
    for (int j = 0; j < 4; ++j) {
      int row = row0 + w * 32 + i * 16 + quad * 4;
      float* Cptr = C + (size_t)row * N + col0 + j * 16 + l16;
#pragma unroll
      for (int rg = 0; rg < 4; ++rg) Cptr[(size_t)rg * N] = acc[i][j][rg];
    }
}

// ---------------- launch ----------------
extern "C" void kernel_launch(void* const* d_in, const int* in_sizes, int n_in,
                              void* d_out, int out_size, void* d_ws, size_t ws_size,
                              hipStream_t stream) {
  const float* x = (const float*)d_in[0];
  const float* Wq = (const float*)d_in[1];
  const float* Wkv = (const float*)d_in[2];
  const float* Wo = (const float*)d_in[3];
  const float* q_scale = (const float*)d_in[4];
  const float* k_scale = (const float*)d_in[5];
  float* out = (float*)d_out;

  char* ws = (char*)d_ws;
  size_t off = 0;
  auto alloc = [&](size_t bytes) {
    void* p = ws + off;
    off += (bytes + 255) & ~(size_t)255;
    return p;
  };
  unsigned short* xb = (unsigned short*)alloc((size_t)MROWS * DM * 2);
  unsigned short* wt1 = (unsigned short*)alloc((size_t)NQKV * DM * 2);   // [Wq^T ; Wkv^T]
  unsigned short* wot = (unsigned short*)alloc((size_t)DM * DM * 2);
  unsigned short* qb = (unsigned short*)alloc((size_t)BATCH * NH * S_LEN * HD * 2);
  unsigned short* kbuf = (unsigned short*)alloc((size_t)BATCH * NKV * S_LEN * HD * 2);
  unsigned short* vrow = (unsigned short*)alloc((size_t)MROWS * NKV * HD * 2);
  unsigned short* vt = (unsigned short*)alloc((size_t)BATCH * NKV * HD * S_LEN * 2);
  unsigned short* ctx = (unsigned short*)alloc((size_t)MROWS * DM * 2);

  cvt_x_kernel<<<(MROWS * DM) / 1024, 256, 0, stream>>>(x, xb, MROWS * DM);
  transpose_all_kernel<<<640, 256, 0, stream>>>(Wq, Wkv, Wo, wt1, wot);

  gemm1_fused<<<dim3(NQKV / 64, MROWS / 128), 256, 0, stream>>>(xb, wt1, q_scale, k_scale,
                                                                qb, kbuf, vrow, DM);
  v_transpose_bf16<<<256, 256, 0, stream>>>(vrow, vt);

  attn_kernel<<<BATCH * NKV * (S_LEN / 32), 256, 0, stream>>>(qb, kbuf, vt, ctx);

  gemm_bt_n64<<<dim3(DM / 64, MROWS / 128), 256, 0, stream>>>(ctx, wot, out, MROWS, DM, DM);
}

// Round 10
// 174.857 us; speedup vs baseline: 1.3855x; 1.0903x over previous
//
#include <hip/hip_runtime.h>

#define S_LEN 2048
#define BATCH 2
#define DM    1024
#define NH    16
#define NKV   4
#define HD    64
#define MROWS (BATCH * S_LEN)   // 4096
#define NQKV  1536              // 1024 q + 512 kv

typedef __attribute__((ext_vector_type(8))) short bf16x8;
typedef __attribute__((ext_vector_type(4))) short s16x4;
typedef __attribute__((ext_vector_type(4))) float f32x4;

__device__ __forceinline__ unsigned short f2bf(float f) {
  unsigned int u = __float_as_uint(f);
  u += 0x7FFF + ((u >> 16) & 1);   // RNE
  return (unsigned short)(u >> 16);
}

__device__ __forceinline__ void gload_lds16(const unsigned short* g, unsigned short* l) {
  __builtin_amdgcn_global_load_lds((const __attribute__((address_space(1))) void*)g,
                                   (__attribute__((address_space(3))) void*)l, 16, 0, 0);
}
__device__ __forceinline__ void gload_lds4(const unsigned short* g, unsigned short* l) {
  __builtin_amdgcn_global_load_lds((const __attribute__((address_space(1))) void*)g,
                                   (__attribute__((address_space(3))) void*)l, 4, 0, 0);
}

// ---------------- x -> bf16 ----------------
__global__ __launch_bounds__(256) void cvt_x_kernel(const float* __restrict__ x,
                                                    unsigned short* __restrict__ xb, int n) {
  int i = (blockIdx.x * 256 + threadIdx.x) * 4;
  if (i < n) {
    float4 v = *reinterpret_cast<const float4*>(x + i);
    xb[i + 0] = f2bf(v.x);
    xb[i + 1] = f2bf(v.y);
    xb[i + 2] = f2bf(v.z);
    xb[i + 3] = f2bf(v.w);
  }
}

// ------- all three W (RxC fp32) -> W^T (CxR bf16) in ONE launch -------
__global__ __launch_bounds__(256) void transpose_all_kernel(const float* __restrict__ Wq,
                                                            const float* __restrict__ Wkv,
                                                            const float* __restrict__ Wo,
                                                            unsigned short* __restrict__ wt1,
                                                            unsigned short* __restrict__ wot) {
  __shared__ float tile[64][65];
  int bid = blockIdx.x;
  const float* in;
  unsigned short* out;
  int R, C, bx, by;
  if (bid < 256) { in = Wq; out = wt1; R = 1024; C = 1024; bx = bid & 15; by = bid >> 4; }
  else if (bid < 384) { int k = bid - 256; in = Wkv; out = wt1 + 1024 * 1024; R = 1024; C = 512; bx = k & 7; by = k >> 3; }
  else { int k = bid - 384; in = Wo; out = wot; R = 1024; C = 1024; bx = k & 15; by = k >> 4; }
  int r0 = by * 64, c0 = bx * 64;
  int t = threadIdx.x;
  int rl = t >> 2, cs = (t & 3) * 16;
#pragma unroll
  for (int k = 0; k < 4; ++k) {
    float4 v = *reinterpret_cast<const float4*>(in + (size_t)(r0 + rl) * C + c0 + cs + 4 * k);
    tile[rl][cs + 4 * k + 0] = v.x;
    tile[rl][cs + 4 * k + 1] = v.y;
    tile[rl][cs + 4 * k + 2] = v.z;
    tile[rl][cs + 4 * k + 3] = v.w;
  }
  __syncthreads();
  int cl = t >> 2, rs = (t & 3) * 16;
  bf16x8 v0, v1;
#pragma unroll
  for (int i = 0; i < 8; ++i) v0[i] = (short)f2bf(tile[rs + i][cl]);
#pragma unroll
  for (int i = 0; i < 8; ++i) v1[i] = (short)f2bf(tile[rs + 8 + i][cl]);
  unsigned short* dst = out + (size_t)(c0 + cl) * R + r0 + rs;
  *reinterpret_cast<bf16x8*>(dst) = v0;
  *reinterpret_cast<bf16x8*>(dst + 8) = v1;
}

// ------- gemm1 FUSED: qkv = xb @ wt1^T, epilogue does RMSNorm+RoPE (q,k) -------
__global__ __launch_bounds__(256) void gemm1_fused(const unsigned short* __restrict__ A,
                                                   const unsigned short* __restrict__ BT,
                                                   const float* __restrict__ q_scale,
                                                   const float* __restrict__ k_scale,
                                                   unsigned short* __restrict__ qb,
                                                   unsigned short* __restrict__ kbuf,
                                                   unsigned short* __restrict__ vrow,
                                                   int K) {
  __shared__ __align__(16) unsigned short As[128 * 64];
  __shared__ __align__(16) unsigned short Bs[64 * 64];
  int bx = blockIdx.x;
  int row0 = blockIdx.y * 128, col0 = bx * 64;
  int t = threadIdx.x;
  int w = t >> 6, lane = t & 63, quad = lane >> 4, l16 = lane & 15;
  int srow = lane >> 3;
  int scol = (lane & 7) * 8;

  f32x4 acc[2][4];
#pragma unroll
  for (int i = 0; i < 2; ++i)
#pragma unroll
    for (int j = 0; j < 4; ++j) acc[i][j] = (f32x4){0.f, 0.f, 0.f, 0.f};

  for (int k0 = 0; k0 < K; k0 += 64) {
#pragma unroll
    for (int j = 0; j < 4; ++j)
      gload_lds16(A + (size_t)(row0 + w * 32 + j * 8 + srow) * K + k0 + scol,
                  &As[(w * 32 + j * 8) * 64]);
#pragma unroll
    for (int j = 0; j < 2; ++j)
      gload_lds16(BT + (size_t)(col0 + w * 16 + j * 8 + srow) * K + k0 + scol,
                  &Bs[(w * 16 + j * 8) * 64]);
    __syncthreads();
#pragma unroll
    for (int ks = 0; ks < 2; ++ks) {
      bf16x8 af[2], bfr[4];
#pragma unroll
      for (int i = 0; i < 2; ++i)
        af[i] = *reinterpret_cast<const bf16x8*>(&As[(w * 32 + i * 16 + l16) * 64 + ks * 32 + quad * 8]);
#pragma unroll
      for (int j = 0; j < 4; ++j)
        bfr[j] = *reinterpret_cast<const bf16x8*>(&Bs[(j * 16 + l16) * 64 + ks * 32 + quad * 8]);
#pragma unroll
      for (int i = 0; i < 2; ++i)
#pragma unroll
        for (int j = 0; j < 4; ++j)
          acc[i][j] = __builtin_amdgcn_mfma_f32_16x16x32_bf16(af[i], bfr[j], acc[i][j], 0, 0, 0);
    }
    __syncthreads();
  }

  if (bx < 20) {
    const float* scale = (bx < 16) ? q_scale : k_scale;
    float post = (bx < 16) ? 1.0f : 0.125f * 1.44269504088896f;
    float sc0 = scale[l16], sc1 = scale[16 + l16], sc2 = scale[32 + l16], sc3 = scale[48 + l16];
    float invf0 = exp2f((float)l16 * (-13.2877123795495f / 32.0f));
    float invf1 = exp2f((float)(l16 + 16) * (-13.2877123795495f / 32.0f));
#pragma unroll
    for (int i = 0; i < 2; ++i)
#pragma unroll
      for (int rg = 0; rg < 4; ++rg) {
        int row = row0 + w * 32 + i * 16 + quad * 4 + rg;
        int b = row >> 11, s = row & 2047;
        float v0 = acc[i][0][rg], v1 = acc[i][1][rg], v2 = acc[i][2][rg], v3 = acc[i][3][rg];
        float ss = v0 * v0 + v1 * v1 + v2 * v2 + v3 * v3;
        ss += __shfl_xor(ss, 1, 64);
        ss += __shfl_xor(ss, 2, 64);
        ss += __shfl_xor(ss, 4, 64);
        ss += __shfl_xor(ss, 8, 64);
        float inv_rms = 1.0f / sqrtf(ss * (1.0f / 64.0f) + 1e-5f);
        float n0 = v0 * inv_rms * sc0, n1 = v1 * inv_rms * sc1;
        float n2 = v2 * inv_rms * sc2, n3 = v3 * inv_rms * sc3;
        float f0 = (float)s * invf0, f1 = (float)s * invf1;
        float c0 = cosf(f0), s0 = sinf(f0), c1 = cosf(f1), s1 = sinf(f1);
        float o0 = (n0 * c0 - n2 * s0) * post;
        float o1 = (n1 * c1 - n3 * s1) * post;
        float o2 = (n0 * s0 + n2 * c0) * post;
        float o3 = (n1 * s1 + n3 * c1) * post;
        unsigned short* dst = (bx < 16)
            ? qb + ((size_t)(b * NH + bx) * S_LEN + s) * HD
            : kbuf + ((size_t)(b * NKV + (bx - 16)) * S_LEN + s) * HD;
        dst[l16] = f2bf(o0);
        dst[16 + l16] = f2bf(o1);
        dst[32 + l16] = f2bf(o2);
        dst[48 + l16] = f2bf(o3);
      }
  } else {
    int kvh = bx - 20;
#pragma unroll
    for (int i = 0; i < 2; ++i)
#pragma unroll
      for (int rg = 0; rg < 4; ++rg) {
        int row = row0 + w * 32 + i * 16 + quad * 4 + rg;
        unsigned short* dst = vrow + (size_t)row * 256 + kvh * 64;
        dst[l16] = f2bf(acc[i][0][rg]);
        dst[16 + l16] = f2bf(acc[i][1][rg]);
        dst[32 + l16] = f2bf(acc[i][2][rg]);
        dst[48 + l16] = f2bf(acc[i][3][rg]);
      }
  }
}

// ------- vrow (b*S+s, kvh*64+d) bf16 -> vt (b*NKV+kvh, d, s) bf16 -------
__global__ __launch_bounds__(256) void v_transpose_bf16(const unsigned short* __restrict__ vrow,
                                                        unsigned short* __restrict__ vt) {
  __shared__ unsigned short tile[64][72];
  int bkv = blockIdx.x >> 5;
  int b = bkv >> 2, kvh = bkv & 3;
  int s0 = (blockIdx.x & 31) * 64;
  int t = threadIdx.x;
  int sl = t >> 2, part = (t & 3) * 16;
  const unsigned short* src = vrow + (size_t)(b * S_LEN + s0 + sl) * 256 + kvh * 64 + part;
  *reinterpret_cast<bf16x8*>(&tile[sl][part]) = *reinterpret_cast<const bf16x8*>(src);
  *reinterpret_cast<bf16x8*>(&tile[sl][part + 8]) = *reinterpret_cast<const bf16x8*>(src + 8);
  __syncthreads();
  int d = t >> 2, sc = (t & 3) * 16;
  bf16x8 a0, a1;
#pragma unroll
  for (int i = 0; i < 8; ++i) a0[i] = (short)tile[sc + i][d];
#pragma unroll
  for (int i = 0; i < 8; ++i) a1[i] = (short)tile[sc + 8 + i][d];
  unsigned short* dst = vt + ((size_t)bkv * 64 + d) * S_LEN + s0 + sc;
  *reinterpret_cast<bf16x8*>(dst) = a0;
  *reinterpret_cast<bf16x8*>(dst + 8) = a1;
}

// ------- causal flash attention: split-S(2), GQA-shared, LDS-staged -------
// 1024 blocks: (z, t32, bkv), heavy tiles first. Block z processes key tiles
// kbi ≡ z (mod 2) of its q-tile (uniform work ±1 iter); fixed-max exp2 softmax
// means partials combine as O=O0+O1, l=l0+l1. Writes unnormalized bf16 O + f32 l.
// K/V double-buffered via async global_load_lds; 3 blocks/CU (12 waves/CU).
#define CH 136                 // shorts per chunk: 256B data + 16B pad
#define TILE_SH (32 * CH)
__global__ __launch_bounds__(256, 3) void attn_kernel(const unsigned short* __restrict__ qb,
                                                      const unsigned short* __restrict__ kbuf,
                                                      const unsigned short* __restrict__ vt,
                                                      unsigned short* __restrict__ Opart,
                                                      float* __restrict__ lpart) {
  __shared__ __align__(16) unsigned short Ks[2][TILE_SH];
  __shared__ __align__(16) unsigned short Vs[2][TILE_SH];
  __shared__ __align__(16) unsigned short PT[4][2][16][72];
  const size_t OZ = (size_t)BATCH * NH * S_LEN * HD;
  const size_t LZ = (size_t)BATCH * NH * S_LEN;
  int t32 = 63 - (int)(blockIdx.x >> 4);   // heavy tiles dispatched first
  int sub = blockIdx.x & 15;
  int z = sub & 1;
  int bkv = sub >> 1;
  int b = bkv >> 2, kvh = bkv & 3;
  int w = threadIdx.x >> 6;                // head within kv group
  int h = kvh * 4 + w;
  int lane = threadIdx.x & 63;
  int quad = lane >> 4, l16 = lane & 15;
  int qa = t32 * 32 + l16;                 // q-group a; group b = qa + 16
  const unsigned short* Q = qb + (size_t)(b * NH + h) * S_LEN * HD;
  const unsigned short* Kh = kbuf + (size_t)(b * NKV + kvh) * S_LEN * HD;
  const unsigned short* Vh = vt + (size_t)(b * NKV + kvh) * HD * S_LEN;

  bf16x8 bqa0 = *reinterpret_cast<const bf16x8*>(Q + (size_t)qa * HD + quad * 8);
  bf16x8 bqa1 = *reinterpret_cast<const bf16x8*>(Q + (size_t)qa * HD + 32 + quad * 8);
  bf16x8 bqb0 = *reinterpret_cast<const bf16x8*>(Q + (size_t)(qa + 16) * HD + quad * 8);
  bf16x8 bqb1 = *reinterpret_cast<const bf16x8*>(Q + (size_t)(qa + 16) * HD + 32 + quad * 8);

  bf16x8 ones;
#pragma unroll
  for (int i = 0; i < 8; ++i) ones[i] = (short)0x3F80;   // bf16 1.0

  f32x4 ot[2][4];
#pragma unroll
  for (int gq = 0; gq < 2; ++gq)
#pragma unroll
    for (int i = 0; i < 4; ++i) ot[gq][i] = (f32x4){0.f, 0.f, 0.f, 0.f};
  f32x4 ol[2] = {(f32x4){0.f, 0.f, 0.f, 0.f}, (f32x4){0.f, 0.f, 0.f, 0.f}};

  int n = (t32 >> 1) + 1;                  // key tiles for this q-tile

  auto stage = [&](int kbase, int dbuf) {
    const unsigned short* kg = Kh + (size_t)(kbase + w * 16) * HD + lane * 2;
    const unsigned short* vg = Vh + (size_t)(w * 16 + (lane >> 5)) * S_LEN + kbase + (lane & 31) * 2;
    unsigned short* kl = &Ks[dbuf][(w * 8) * CH];
    unsigned short* vl = &Vs[dbuf][(w * 8) * CH];
#pragma unroll
    for (int c = 0; c < 8; ++c) {
      gload_lds4(kg + (size_t)(2 * c) * HD, kl + c * CH);
      gload_lds4(vg + (size_t)(2 * c) * S_LEN, vl + c * CH);
    }
  };

  if (z < n) {
    stage(z << 6, 0);
    __syncthreads();

    for (int kb = z; kb < n; kb += 2) {
      int dbuf = (kb >> 1) & 1;
      bool diag = (kb == n - 1);
      if (kb + 2 < n) stage((kb + 2) << 6, dbuf ^ 1);
      int kbase = kb << 6;
      const unsigned short* Kd = Ks[dbuf];
      const unsigned short* Vd = Vs[dbuf];

      f32x4 sa[4], sb[4];
#pragma unroll
      for (int km = 0; km < 4; ++km) {
        int ch = km * 8 + (l16 >> 1);
        int base = ch * CH + (l16 & 1) * 64;
        bf16x8 k0 = *reinterpret_cast<const bf16x8*>(&Kd[base + quad * 8]);
        bf16x8 k1 = *reinterpret_cast<const bf16x8*>(&Kd[base + 32 + quad * 8]);
        f32x4 s = {0.f, 0.f, 0.f, 0.f};
        s = __builtin_amdgcn_mfma_f32_16x16x32_bf16(k0, bqa0, s, 0, 0, 0);
        s = __builtin_amdgcn_mfma_f32_16x16x32_bf16(k1, bqa1, s, 0, 0, 0);
        sa[km] = s;
        f32x4 s2 = {0.f, 0.f, 0.f, 0.f};
        s2 = __builtin_amdgcn_mfma_f32_16x16x32_bf16(k0, bqb0, s2, 0, 0, 0);
        s2 = __builtin_amdgcn_mfma_f32_16x16x32_bf16(k1, bqb1, s2, 0, 0, 0);
        sb[km] = s2;
      }
      if (diag) {
#pragma unroll
        for (int km = 0; km < 4; ++km)
#pragma unroll
          for (int rg = 0; rg < 4; ++rg) {
            int key = kbase + km * 16 + quad * 4 + rg;
            if (key > qa) sa[km][rg] = -1e30f;
            if (key > qa + 16) sb[km][rg] = -1e30f;
          }
      }
#pragma unroll
      for (int km = 0; km < 4; ++km) {
        float a0 = exp2f(sa[km][0]), a1 = exp2f(sa[km][1]);
        float a2 = exp2f(sa[km][2]), a3 = exp2f(sa[km][3]);
        uint2 pw;
        pw.x = __builtin_amdgcn_perm(__float_as_uint(a1), __float_as_uint(a0), 0x07060302);
        pw.y = __builtin_amdgcn_perm(__float_as_uint(a3), __float_as_uint(a2), 0x07060302);
        *reinterpret_cast<uint2*>(&PT[w][0][l16][km * 16 + quad * 4]) = pw;
        float b0 = exp2f(sb[km][0]), b1 = exp2f(sb[km][1]);
        float b2 = exp2f(sb[km][2]), b3 = exp2f(sb[km][3]);
        uint2 qw;
        qw.x = __builtin_amdgcn_perm(__float_as_uint(b1), __float_as_uint(b0), 0x07060302);
        qw.y = __builtin_amdgcn_perm(__float_as_uint(b3), __float_as_uint(b2), 0x07060302);
        *reinterpret_cast<uint2*>(&PT[w][1][l16][km * 16 + quad * 4]) = qw;
      }
      bf16x8 pa0 = *reinterpret_cast<const bf16x8*>(&PT[w][0][l16][quad * 8]);
      bf16x8 pa1 = *reinterpret_cast<const bf16x8*>(&PT[w][0][l16][32 + quad * 8]);
      bf16x8 pb0 = *reinterpret_cast<const bf16x8*>(&PT[w][1][l16][quad * 8]);
      bf16x8 pb1 = *reinterpret_cast<const bf16x8*>(&PT[w][1][l16][32 + quad * 8]);
      ol[0] = __builtin_amdgcn_mfma_f32_16x16x32_bf16(ones, pa0, ol[0], 0, 0, 0);
      ol[0] = __builtin_amdgcn_mfma_f32_16x16x32_bf16(ones, pa1, ol[0], 0, 0, 0);
      ol[1] = __builtin_amdgcn_mfma_f32_16x16x32_bf16(ones, pb0, ol[1], 0, 0, 0);
      ol[1] = __builtin_amdgcn_mfma_f32_16x16x32_bf16(ones, pb1, ol[1], 0, 0, 0);
#pragma unroll
      for (int dm = 0; dm < 4; ++dm) {
        int ch = dm * 8 + (l16 >> 1);
        int base = ch * CH + (l16 & 1) * 64;
        bf16x8 v0 = *reinterpret_cast<const bf16x8*>(&Vd[base + quad * 8]);
        bf16x8 v1 = *reinterpret_cast<const bf16x8*>(&Vd[base + 32 + quad * 8]);
        ot[0][dm] = __builtin_amdgcn_mfma_f32_16x16x32_bf16(v0, pa0, ot[0][dm], 0, 0, 0);
        ot[0][dm] = __builtin_amdgcn_mfma_f32_16x16x32_bf16(v1, pa1, ot[0][dm], 0, 0, 0);
        ot[1][dm] = __builtin_amdgcn_mfma_f32_16x16x32_bf16(v0, pb0, ot[1][dm], 0, 0, 0);
        ot[1][dm] = __builtin_amdgcn_mfma_f32_16x16x32_bf16(v1, pb1, ot[1][dm], 0, 0, 0);
      }
      __syncthreads();   // drains prefetch (issued a full phase ago) + buffer swap
    }
  }

  // write unnormalized bf16 O partial + fp32 l partial for this z
  unsigned short* Oz = Opart + (size_t)z * OZ;
  float* lz = lpart + (size_t)z * LZ;
#pragma unroll
  for (int gq = 0; gq < 2; ++gq) {
    size_t base = ((size_t)(b * NH + h) * S_LEN + qa + gq * 16) * HD;
#pragma unroll
    for (int dm = 0; dm < 4; ++dm) {
      s16x4 pv;
#pragma unroll
      for (int rg = 0; rg < 4; ++rg) pv[rg] = (short)f2bf(ot[gq][dm][rg]);
      *reinterpret_cast<s16x4*>(Oz + base + dm * 16 + quad * 4) = pv;
    }
  }
  if (quad == 0) {
    size_t lb = (size_t)(b * NH + h) * S_LEN + t32 * 32 + l16;
    lz[lb] = ol[0][0];
    lz[lb + 16] = ol[1][0];
  }
}

// ------- combine split-S partials: ctx = (O0+O1)/(l0+l1), bf16 -------
__global__ __launch_bounds__(256) void attn_combine_kernel(const unsigned short* __restrict__ Opart,
                                                           const float* __restrict__ lpart,
                                                           unsigned short* __restrict__ ctx) {
  const size_t OZ = (size_t)BATCH * NH * S_LEN * HD;
  const size_t LZ = (size_t)BATCH * NH * S_LEN;
  int i8 = blockIdx.x * 256 + threadIdx.x;   // 8 elems per thread
  size_t i = (size_t)i8 * 8;
  int row = i8 >> 3;                          // (b*NH+h)*S_LEN + q
  bf16x8 a = *reinterpret_cast<const bf16x8*>(Opart + i);
  bf16x8 c = *reinterpret_cast<const bf16x8*>(Opart + OZ + i);
  float inv = 1.0f / (lpart[row] + lpart[LZ + row]);
  int q = row & 2047;
  int bh = row >> 11;
  int b = bh >> 4, h = bh & 15;
  int d0 = (i8 & 7) * 8;
  bf16x8 o;
#pragma unroll
  for (int k = 0; k < 8; ++k) {
    float fa = __uint_as_float(((unsigned int)(unsigned short)a[k]) << 16);
    float fc = __uint_as_float(((unsigned int)(unsigned short)c[k]) << 16);
    o[k] = (short)f2bf((fa + fc) * inv);
  }
  *reinterpret_cast<bf16x8*>(ctx + ((size_t)(b * S_LEN + q)) * DM + h * HD + d0) = o;
}

// ------- gemm2: out = ctx @ wot^T, 128x64 tile, direct fp32 C -------
__global__ __launch_bounds__(256) void gemm_bt_n64(const unsigned short* __restrict__ A,
                                                   const unsigned short* __restrict__ BT,
                                                   float* __restrict__ C,
                                                   int M, int N, int K) {
  __shared__ __align__(16) unsigned short As[128 * 64];
  __shared__ __align__(16) unsigned short Bs[64 * 64];
  int row0 = blockIdx.y * 128, col0 = blockIdx.x * 64;
  int t = threadIdx.x;
  int w = t >> 6, lane = t & 63, quad = lane >> 4, l16 = lane & 15;
  int srow = lane >> 3;
  int scol = (lane & 7) * 8;

  f32x4 acc[2][4];
#pragma unroll
  for (int i = 0; i < 2; ++i)
#pragma unroll
    for (int j = 0; j < 4; ++j) acc[i][j] = (f32x4){0.f, 0.f, 0.f, 0.f};

  for (int k0 = 0; k0 < K; k0 += 64) {
#pragma unroll
    for (int j = 0; j < 4; ++j)
      gload_lds16(A + (size_t)(row0 + w * 32 + j * 8 + srow) * K + k0 + scol,
                  &As[(w * 32 + j * 8) * 64]);
#pragma unroll
    for (int j = 0; j < 2; ++j)
      gload_lds16(BT + (size_t)(col0 + w * 16 + j * 8 + srow) * K + k0 + scol,
                  &Bs[(w * 16 + j * 8) * 64]);
    __syncthreads();
#pragma unroll
    for (int ks = 0; ks < 2; ++ks) {
      bf16x8 af[2], bfr[4];
#pragma unroll
      for (int i = 0; i < 2; ++i)
        af[i] = *reinterpret_cast<const bf16x8*>(&As[(w * 32 + i * 16 + l16) * 64 + ks * 32 + quad * 8]);
#pragma unroll
      for (int j = 0; j < 4; ++j)
        bfr[j] = *reinterpret_cast<const bf16x8*>(&Bs[(j * 16 + l16) * 64 + ks * 32 + quad * 8]);
#pragma unroll
      for (int i = 0; i < 2; ++i)
#pragma unroll
        for (int j = 0; j < 4; ++j)
          acc[i][j] = __builtin_amdgcn_mfma_f32_16x16x32_bf16(af[i], bfr[j], acc[i][j], 0, 0, 0);
    }
    __syncthreads();
  }
#pragma unroll
  for (int i = 0; i < 2; ++i)
#pragma unroll
    for (int j = 0; j < 4; ++j) {
      int row = row0 + w * 32 + i * 16 + quad * 4;
      float* Cptr = C + (size_t)row * N + col0 + j * 16 + l16;
#pragma unroll
      for (int rg = 0; rg < 4; ++rg) Cptr[(size_t)rg * N] = acc[i][j][rg];
    }
}

// ---------------- launch ----------------
extern "C" void kernel_launch(void* const* d_in, const int* in_sizes, int n_in,
                              void* d_out, int out_size, void* d_ws, size_t ws_size,
                              hipStream_t stream) {
  const float* x = (const float*)d_in[0];
  const float* Wq = (const float*)d_in[1];
  const float* Wkv = (const float*)d_in[2];
  const float* Wo = (const float*)d_in[3];
  const float* q_scale = (const float*)d_in[4];
  const float* k_scale = (const float*)d_in[5];
  float* out = (float*)d_out;

  char* ws = (char*)d_ws;
  size_t off = 0;
  auto alloc = [&](size_t bytes) {
    void* p = ws + off;
    off += (bytes + 255) & ~(size_t)255;
    return p;
  };
  unsigned short* xb = (unsigned short*)alloc((size_t)MROWS * DM * 2);
  unsigned short* wt1 = (unsigned short*)alloc((size_t)NQKV * DM * 2);   // [Wq^T ; Wkv^T]
  unsigned short* wot = (unsigned short*)alloc((size_t)DM * DM * 2);
  unsigned short* qb = (unsigned short*)alloc((size_t)BATCH * NH * S_LEN * HD * 2);
  unsigned short* kbuf = (unsigned short*)alloc((size_t)BATCH * NKV * S_LEN * HD * 2);
  unsigned short* vrow = (unsigned short*)alloc((size_t)MROWS * NKV * HD * 2);
  unsigned short* vt = (unsigned short*)alloc((size_t)BATCH * NKV * HD * S_LEN * 2);
  unsigned short* ctx = (unsigned short*)alloc((size_t)MROWS * DM * 2);
  unsigned short* Opart = (unsigned short*)alloc(2 * (size_t)BATCH * NH * S_LEN * HD * 2);
  float* lpart = (float*)alloc(2 * (size_t)BATCH * NH * S_LEN * 4);

  cvt_x_kernel<<<(MROWS * DM) / 1024, 256, 0, stream>>>(x, xb, MROWS * DM);
  transpose_all_kernel<<<640, 256, 0, stream>>>(Wq, Wkv, Wo, wt1, wot);

  gemm1_fused<<<dim3(NQKV / 64, MROWS / 128), 256, 0, stream>>>(xb, wt1, q_scale, k_scale,
                                                                qb, kbuf, vrow, DM);
  v_transpose_bf16<<<256, 256, 0, stream>>>(vrow, vt);

  attn_kernel<<<1024, 256, 0, stream>>>(qb, kbuf, vt, Opart, lpart);
  attn_combine_kernel<<<(BATCH * NH * S_LEN * HD / 8) / 256, 256, 0, stream>>>(Opart, lpart, ctx);

  gemm_bt_n64<<<dim3(DM / 64, MROWS / 128), 256, 0, stream>>>(ctx, wot, out, MROWS, DM, DM);
}